// Round 8
// baseline (81053.717 us; speedup 1.0000x reference)
//
#include <hip/hip_runtime.h>
#include <hip/hip_bf16.h>

using bf16 = __hip_bfloat16;
static __device__ __forceinline__ float ldin(const void* p, size_t i, int f){
  return f ? __bfloat162float(((const bf16*)p)[i]) : ((const float*)p)[i];
}

#define Bc 32
#define NPGc 290
#define Nn 9280
#define Ec 74240
#define LPc 900
#define INFc 75
#define Dd 128
#define HKc 768
#define LQ 885

// Per-array dtype probe. Reads C values as bf16 (safe under either dtype).
// fp32 if: any |x|>=1e3 (incl. NaN/Inf), or (all even idx == 0 and some odd != 0).
__global__ void k_probe2(int* flag, const void* p, int C){
  __shared__ int big, evenNZ, oddNZ;
  if (threadIdx.x==0){ big=0; evenNZ=0; oddNZ=0; }
  __syncthreads();
  for (int i = threadIdx.x; i < C; i += blockDim.x){
    float v = __bfloat162float(((const bf16*)p)[i]);
    float a = fabsf(v);
    if (!(a <= 1e3f)) atomicOr(&big, 1);
    if ((i & 1) == 0){ if (v != 0.f) atomicOr(&evenNZ, 1); }
    else             { if (v != 0.f) atomicOr(&oddNZ, 1); }
  }
  __syncthreads();
  if (threadIdx.x==0)
    *flag = (big || (!evenNZ && oddNZ)) ? 0 : 1;   // 0=fp32, 1=bf16
}

__global__ void k_sentinel(float* out, float val){
  int t = threadIdx.x;
  if (t < 128) out[t] = val;
}

// ---------------- GCN ----------------
__global__ void k_h0(float* __restrict__ h0, const void* nh, const void* Wi, const int* fl){
  int n = blockIdx.x, j = threadIdx.x;
  int fn = fl[0], fw = fl[4];
  float s = 0.f;
  for (int k=0;k<INFc;k++) s += ldin(nh,(size_t)n*INFc+k,fn) * ldin(Wi,(size_t)k*Dd+j,fw);
  h0[(size_t)n*Dd + j] = s;
}

__global__ void k_scatter(float* __restrict__ agg, const float* __restrict__ h,
                          const int* __restrict__ src, const int* __restrict__ dst){
  long long idx = (long long)blockIdx.x*blockDim.x + threadIdx.x;
  if (idx >= (long long)Ec*Dd) return;
  int e = (int)(idx / Dd), c = (int)(idx % Dd);
  atomicAdd(&agg[(size_t)dst[e]*Dd + c], h[(size_t)src[e]*Dd + c]);
}

__global__ void k_gcn(float* __restrict__ out, const float* __restrict__ agg, const float* __restrict__ h,
                      const void* W, const void* bvec, const void* Wr, const void* br,
                      const int* fl, size_t woW, size_t wob){
  int n = blockIdx.x, j = threadIdx.x;
  int fW = fl[5], fb = fl[6], fWr = fl[7], fbr = fl[8];
  float s1 = ldin(bvec,wob+j,fb), s2 = ldin(br,wob+j,fbr);
  for (int k=0;k<Dd;k++){
    s1 += agg[(size_t)n*Dd + k] * ldin(W, woW+(size_t)k*Dd+j,fW);
    s2 += h[(size_t)n*Dd + k]   * ldin(Wr,woW+(size_t)k*Dd+j,fWr);
  }
  out[(size_t)n*Dd + j] = fmaxf(s1,0.f) + fmaxf(s2,0.f);
}

// ---------------- ProteinCNN ----------------
__global__ void k_embed(float* __restrict__ x, const int* __restrict__ vp, const void* emb, const int* fl){
  int t = blockIdx.x*blockDim.x + threadIdx.x;
  int d = blockIdx.y, b = blockIdx.z;
  if (t >= LPc) return;
  int fe = fl[9];
  int tok = vp[b*LPc + t];
  x[((size_t)b*Dd + d)*LPc + t] = ldin(emb,(size_t)tok*Dd+d,fe);
}

__global__ void k_conv(float* __restrict__ y, const float* __restrict__ x, const void* w,
                       const void* cb, const int* fl, int fiw, int Lin, int Lout, int KW, int cbo){
  int t = blockIdx.x*blockDim.x + threadIdx.x;
  int o = blockIdx.y, b = blockIdx.z;
  if (t >= Lout) return;
  int fw = fl[fiw], fcb = fl[13];
  float s = ldin(cb,(size_t)cbo+o,fcb);
  for (int i=0;i<Dd;i++)
    for (int k=0;k<KW;k++)
      s += x[((size_t)b*Dd + i)*Lin + t + k] * ldin(w,(size_t)(o*Dd + i)*KW + k,fw);
  y[((size_t)b*Dd + o)*Lout + t] = fmaxf(s, 0.f);
}

__global__ void k_bnc_stats(float* __restrict__ mean, float* __restrict__ rstd,
                            const float* __restrict__ y, int Lout){
  int c = blockIdx.x;
  float s=0.f, ss=0.f;
  int cnt = Bc*Lout;
  for (int i = threadIdx.x; i < cnt; i += blockDim.x){
    int b = i / Lout, t = i - b*Lout;
    float v = y[((size_t)b*Dd+c)*Lout + t];
    s += v; ss += v*v;
  }
  __shared__ float rs[256], rss[256];
  rs[threadIdx.x]=s; rss[threadIdx.x]=ss; __syncthreads();
  for (int st=128; st>0; st>>=1){
    if (threadIdx.x<st){ rs[threadIdx.x]+=rs[threadIdx.x+st]; rss[threadIdx.x]+=rss[threadIdx.x+st]; }
    __syncthreads();
  }
  if (threadIdx.x==0){
    float m = rs[0]/cnt; float v = rss[0]/cnt - m*m; if (v<0.f) v=0.f;
    mean[c]=m; rstd[c]=rsqrtf(v+1e-5f);
  }
}

__global__ void k_bnc_apply(float* __restrict__ y, const float* __restrict__ mean, const float* __restrict__ rstd,
                            const void* g, const void* bb, const int* fl, int Lout, int go){
  int t = blockIdx.x*blockDim.x + threadIdx.x;
  int c = blockIdx.y, b = blockIdx.z;
  if (t >= Lout) return;
  int fg = fl[14], fb = fl[15];
  size_t idx = ((size_t)b*Dd + c)*Lout + t;
  y[idx] = (y[idx]-mean[c])*rstd[c]*ldin(g,(size_t)go+c,fg) + ldin(bb,(size_t)go+c,fb);
}

// ---------------- BAN (direct) ----------------
__global__ void k_qgemm8(float* __restrict__ q, const float* __restrict__ x,
                         const void* W, const void* bias, const int* fl, int b0){
  int j = blockIdx.x*blockDim.x + threadIdx.x;
  int t = blockIdx.y, bl = blockIdx.z;
  if (j >= HKc) return;
  int fW = fl[18], fb = fl[19];
  float s = ldin(bias,j,fb);
  for (int d=0; d<Dd; d++)
    s += x[((size_t)(b0+bl)*Dd + d)*LQ + t] * ldin(W,(size_t)d*HKc+j,fW);
  q[((size_t)bl*LQ + t)*HKc + j] = fmaxf(s, 0.f);
}

__global__ void k_vgemm8(float* __restrict__ v, const float* __restrict__ vd,
                         const void* W, const void* bias, const int* fl, int b0){
  int j = blockIdx.x*blockDim.x + threadIdx.x;
  int r = blockIdx.y;
  if (j >= HKc) return;
  int fW = fl[16], fb = fl[17];
  float s = ldin(bias,j,fb);
  for (int d=0; d<Dd; d++)
    s += vd[(size_t)(b0*NPGc + r)*Dd + d] * ldin(W,(size_t)d*HKc+j,fW);
  v[(size_t)r*HKc + j] = fmaxf(s,0.f);
}

__global__ void k_a2(float* __restrict__ A2o, const float* __restrict__ V,
                     const float* __restrict__ Q, const void* hm, const void* hb, const int* fl){
  int n = blockIdx.x*blockDim.x + threadIdx.x;
  int m = blockIdx.y, bl = blockIdx.z;
  if (n >= LQ) return;
  int fh = fl[20], fhb = fl[21];
  const float* Vr = V + ((size_t)bl*NPGc + m)*HKc;
  const float* Qr = Q + ((size_t)bl*LQ + n)*HKc;
  float s = 0.f;
  for (int k=0;k<HKc;k++)
    s += Vr[k] * (ldin(hm,k,fh) + ldin(hm,(size_t)HKc+k,fh)) * Qr[k];
  A2o[((size_t)bl*NPGc + m)*LQ + n] = s + ldin(hb,0,fhb) + ldin(hb,1,fhb);
}

__global__ void k_tmat(float* __restrict__ T, const float* __restrict__ A2o,
                       const float* __restrict__ Q){
  int j = blockIdx.x*blockDim.x + threadIdx.x;
  int m = blockIdx.y, bl = blockIdx.z;
  if (j >= HKc) return;
  const float* Ar = A2o + ((size_t)bl*NPGc + m)*LQ;
  const float* Qb = Q + (size_t)bl*LQ*HKc + j;
  float s = 0.f;
  for (int qq=0; qq<LQ; qq++)
    s += Ar[qq] * Qb[(size_t)qq*HKc];
  T[((size_t)bl*NPGc + m)*HKc + j] = s;
}

__global__ void k_fdot(float* __restrict__ f, const float* __restrict__ V,
                       const float* __restrict__ T, int b0){
  int k = blockIdx.x*blockDim.x + threadIdx.x;
  int bl = blockIdx.y;
  if (k >= HKc) return;
  const float* Vb = V + (size_t)bl*NPGc*HKc + k;
  const float* Tb = T + (size_t)bl*NPGc*HKc + k;
  float s=0.f;
  for (int v=0; v<NPGc; v++) s += Vb[(size_t)v*HKc]*Tb[(size_t)v*HKc];
  f[(size_t)(b0+bl)*HKc + k] = s;
}

__global__ void k_pool(float* __restrict__ fp, const float* __restrict__ f){
  int idx = blockIdx.x*blockDim.x + threadIdx.x;
  if (idx >= Bc*256) return;
  int b = idx / 256, c = idx % 256;
  fp[b*256 + c] = f[(size_t)b*HKc + c*3] + f[(size_t)b*HKc + c*3+1] + f[(size_t)b*HKc + c*3+2];
}

// ---------------- tail ----------------
__global__ void k_bnfeat(float* __restrict__ y, const float* __restrict__ x, const void* g,
                         const void* bb, const int* fl, int fig, int fib, int C){
  int c = blockIdx.x; int b = threadIdx.x; // 32 threads
  __shared__ float buf[32];
  __shared__ float mv[2];
  int fg = fl[fig], fbb = fl[fib];
  float v = x[b*C + c];
  buf[b] = v;
  __syncthreads();
  if (b == 0){
    float s = 0.f;
    for (int i=0;i<32;i++) s += buf[i];
    float m = s/32.f;
    float vs = 0.f;
    for (int i=0;i<32;i++){ float d = buf[i]-m; vs += d*d; }
    mv[0] = m; mv[1] = vs/32.f;
  }
  __syncthreads();
  y[b*C + c] = (v - mv[0])*rsqrtf(mv[1]+1e-5f)*ldin(g,c,fg) + ldin(bb,c,fbb);
}

__global__ void k_mlp(float* __restrict__ out, const float* __restrict__ in, const void* W,
                      const void* bias, const int* fl, int fiW, int fiB, int K, int Nc, int doRelu){
  int j = blockIdx.x*blockDim.x + threadIdx.x;
  int b = blockIdx.y;
  if (j >= Nc) return;
  int fW = fl[fiW], fb = fl[fiB];
  float s = ldin(bias,j,fb);
  for (int k=0;k<K;k++) s += in[b*K + k]*ldin(W,(size_t)k*Nc+j,fW);
  if (doRelu) s = fmaxf(s, 0.f);
  out[b*Nc + j] = s;
}

__global__ void k_score(float* __restrict__ sc, const float* __restrict__ h, const void* w,
                        const void* bb, const int* fl){
  int b = threadIdx.x; if (b>=32) return;
  int fw = fl[30], fb = fl[31];
  float s = ldin(bb,0,fb);
  for (int k=0;k<Dd;k++) s += h[b*Dd+k]*ldin(w,k,fw);
  sc[b] = s;
}

// FP32 output: out[4b+0..3] = score_o[b], s1[b], s2[b], loss
__global__ void k_out(float* __restrict__ out, const float* __restrict__ scores){
  int t = threadIdx.x;
  __shared__ float loss_s;
  if (t == 0){
    float sn1[32], sn2[32];
    for (int i=0;i<32;i++){
      float a = scores[32+i]; sn1[i] = a / fmaxf(fabsf(a), 1e-12f);
      float c = scores[64+i]; sn2[i] = c / fmaxf(fabsf(c), 1e-12f);
    }
    float acc = 0.f;
    for (int i=0;i<32;i++){
      float mx = -1e30f;
      for (int j=0;j<32;j++) mx = fmaxf(mx, sn1[i]*sn2[j]);
      float se = 0.f;
      for (int j=0;j<32;j++) se += expf(sn1[i]*sn2[j]-mx);
      acc += sn1[i]*sn2[i] - (mx + logf(se));
    }
    loss_s = -acc/32.f;
  }
  __syncthreads();
  out[t*4+0] = scores[t];
  out[t*4+1] = scores[32+t];
  out[t*4+2] = scores[64+t];
  out[t*4+3] = loss_s;
}

extern "C" void kernel_launch(void* const* d_in, const int* in_sizes, int n_in,
                              void* d_out, int out_size, void* d_ws, size_t ws_size,
                              hipStream_t stream){
  static const int exp_sizes[38] = {
    Nn*INFc, Ec, Ec, Bc*LPc, INFc*Dd,
    9*Dd*Dd, 9*Dd, 9*Dd*Dd, 9*Dd,
    26*Dd, Dd*Dd*3, Dd*Dd*6, Dd*Dd*9, 3*Dd, 3*Dd, 3*Dd,
    Dd*HKc, HKc, Dd*HKc, HKc, 2*HKc, 2, 256, 256,
    256*512, 512, 512*512, 512, 512*128, 128, 128, 1,
    512, 512, 512, 512, 128, 128 };
  if (n_in != 38){ k_sentinel<<<1,128,0,stream>>>((float*)d_out, 2000.f + n_in); return; }
  for (int i=0;i<38;i++){
    if (in_sizes[i] != exp_sizes[i]){
      k_sentinel<<<1,128,0,stream>>>((float*)d_out, 1000.f + i); return;
    }
  }

  const int* esrc = (const int*)d_in[1];
  const int* edst = (const int*)d_in[2];
  const int* vp   = (const int*)d_in[3];

  float* ws = (float*)d_ws;
  size_t off = 0;
  auto alloc = [&](size_t n){ float* p = ws + off; off += n; return p; };

  const size_t NDsz  = (size_t)Nn*Dd;
  const size_t CNNB  = (size_t)Bc*Dd*LPc;
  const size_t VSZ   = (size_t)8*NPGc*HKc;
  const size_t QSZ   = (size_t)8*LQ*HKc;
  const size_t A2SZ  = (size_t)8*NPGc*LQ;
  const size_t ARENA = NDsz + VSZ + QSZ + A2SZ + VSZ;

  int*   flags = (int*)alloc(64);   // 38 per-array dtype flags
  float* fbuf = alloc((size_t)Bc*HKc);
  float* fpool= alloc((size_t)Bc*256);
  float* hh1  = alloc((size_t)Bc*512);
  float* hh2  = alloc((size_t)Bc*512);
  float* hh3  = alloc((size_t)Bc*128);
  float* sc   = alloc(96);
  float* bnm  = alloc(128);
  float* bnr  = alloc(128);
  float* cnnOut = alloc((size_t)Bc*Dd*LQ);
  float* arena = alloc(ARENA);

  float* e0 = arena;
  float* e1 = arena + CNNB;
  float* A0 = arena;
  float* A1 = arena + NDsz;
  float* A2t= arena + 2*NDsz;
  float* A3 = arena + 3*NDsz;
  float* vbuf = arena + NDsz;
  float* qbuf = vbuf + VSZ;
  float* a2b  = qbuf + QSZ;
  float* tb   = a2b + A2SZ;

  // ---- per-array dtype probes (skip int arrays 1,2,3) ----
  for (int i=0;i<38;i++){
    if (i==1 || i==2 || i==3) continue;
    int C = exp_sizes[i]; if (C > 32768) C = 32768;
    k_probe2<<<1,256,0,stream>>>(flags+i, d_in[i], C);
  }

  // ---- ProteinCNN -> cnnOut ----
  k_embed<<<dim3((LPc+127)/128, Dd, Bc),128,0,stream>>>(e0, vp, d_in[9], flags);
  k_conv<<<dim3((898+127)/128, Dd, Bc),128,0,stream>>>(e1, e0, d_in[10], d_in[13], flags, 10, 900, 898, 3, 0);
  k_bnc_stats<<<Dd,256,0,stream>>>(bnm,bnr,e1,898);
  k_bnc_apply<<<dim3((898+127)/128, Dd, Bc),128,0,stream>>>(e1,bnm,bnr,d_in[14],d_in[15],flags,898,0);
  k_conv<<<dim3((893+127)/128, Dd, Bc),128,0,stream>>>(e0, e1, d_in[11], d_in[13], flags, 11, 898, 893, 6, 128);
  k_bnc_stats<<<Dd,256,0,stream>>>(bnm,bnr,e0,893);
  k_bnc_apply<<<dim3((893+127)/128, Dd, Bc),128,0,stream>>>(e0,bnm,bnr,d_in[14],d_in[15],flags,893,128);
  k_conv<<<dim3((885+127)/128, Dd, Bc),128,0,stream>>>(cnnOut, e0, d_in[12], d_in[13], flags, 12, 893, 885, 9, 256);
  k_bnc_stats<<<Dd,256,0,stream>>>(bnm,bnr,cnnOut,885);
  k_bnc_apply<<<dim3((885+127)/128, Dd, Bc),128,0,stream>>>(cnnOut,bnm,bnr,d_in[14],d_in[15],flags,885,256);

  // ---- three GCN branches + direct BAN + MLPs ----
  long long scat_thr = (long long)Ec*Dd;
  int scat_blocks = (int)((scat_thr + 255)/256);
  for (int g=0; g<3; g++){
    k_h0<<<Nn,Dd,0,stream>>>(A1, d_in[0], d_in[4], flags);
    hipMemsetAsync(A2t, 0, NDsz*sizeof(float), stream);
    k_scatter<<<scat_blocks,256,0,stream>>>(A2t, A1, esrc, edst);
    { size_t wo=(size_t)(g*3+0);
      k_gcn<<<Nn,Dd,0,stream>>>(A3, A2t, A1, d_in[5], d_in[6], d_in[7], d_in[8], flags, wo*Dd*Dd, wo*Dd); }
    hipMemsetAsync(A2t, 0, NDsz*sizeof(float), stream);
    k_scatter<<<scat_blocks,256,0,stream>>>(A2t, A3, esrc, edst);
    { size_t wo=(size_t)(g*3+1);
      k_gcn<<<Nn,Dd,0,stream>>>(A1, A2t, A3, d_in[5], d_in[6], d_in[7], d_in[8], flags, wo*Dd*Dd, wo*Dd); }
    hipMemsetAsync(A2t, 0, NDsz*sizeof(float), stream);
    k_scatter<<<scat_blocks,256,0,stream>>>(A2t, A1, esrc, edst);
    { size_t wo=(size_t)(g*3+2);
      k_gcn<<<Nn,Dd,0,stream>>>(A0, A2t, A1, d_in[5], d_in[6], d_in[7], d_in[8], flags, wo*Dd*Dd, wo*Dd); }

    for (int c8=0; c8<4; c8++){
      int b0 = c8*8;
      k_vgemm8<<<dim3(3, 8*NPGc),256,0,stream>>>(vbuf, A0, d_in[16], d_in[17], flags, b0);
      k_qgemm8<<<dim3(3, LQ, 8),256,0,stream>>>(qbuf, cnnOut, d_in[18], d_in[19], flags, b0);
      k_a2<<<dim3((LQ+255)/256, NPGc, 8),256,0,stream>>>(a2b, vbuf, qbuf, d_in[20], d_in[21], flags);
      k_tmat<<<dim3(3, NPGc, 8),256,0,stream>>>(tb, a2b, qbuf);
      k_fdot<<<dim3(3, 8),256,0,stream>>>(fbuf, vbuf, tb, b0);
    }

    k_pool<<<(Bc*256+255)/256,256,0,stream>>>(fpool, fbuf);
    k_bnfeat<<<256,32,0,stream>>>(fpool, fpool, d_in[22], d_in[23], flags, 22, 23, 256);
    k_mlp<<<dim3(2,Bc),256,0,stream>>>(hh1, fpool, d_in[24], d_in[25], flags, 24, 25, 256, 512, 1);
    k_bnfeat<<<512,32,0,stream>>>(hh1,hh1,d_in[32],d_in[33],flags,32,33,512);
    k_mlp<<<dim3(2,Bc),256,0,stream>>>(hh2, hh1, d_in[26], d_in[27], flags, 26, 27, 512, 512, 1);
    k_bnfeat<<<512,32,0,stream>>>(hh2,hh2,d_in[34],d_in[35],flags,34,35,512);
    k_mlp<<<dim3(1,Bc),256,0,stream>>>(hh3, hh2, d_in[28], d_in[29], flags, 28, 29, 512, 128, 1);
    k_bnfeat<<<128,32,0,stream>>>(hh3,hh3,d_in[36],d_in[37],flags,36,37,128);
    k_score<<<1,32,0,stream>>>(sc + 32*g, hh3, d_in[30], d_in[31], flags);
  }

  k_out<<<1,32,0,stream>>>((float*)d_out, sc);
}

// Round 9
// 5672.795 us; speedup vs baseline: 14.2881x; 14.2881x over previous
//
#include <hip/hip_runtime.h>
#include <hip/hip_bf16.h>

#define Bc 32
#define NPGc 290
#define Nn 9280
#define Ec 74240
#define LPc 900
#define INFc 75
#define Dd 128
#define HKc 768
#define LQ 885
#define CHT 128   // q-chunk timesteps

__global__ void k_sentinel(float* out, float val){
  int t = threadIdx.x;
  if (t < 128) out[t] = val;
}

// ---------------- GCN ----------------
// h0 = node_h @ W_init  [9280,75]x[75,128]; one block per row, A-row in LDS
__global__ void k_h0(float* __restrict__ h0, const float* __restrict__ nh, const float* __restrict__ Wi){
  int n = blockIdx.x, j = threadIdx.x;
  __shared__ float arow[INFc];
  if (j < INFc) arow[j] = nh[(size_t)n*INFc + j];
  __syncthreads();
  float s = 0.f;
  #pragma unroll 5
  for (int k=0;k<INFc;k++) s += arow[k]*Wi[(size_t)k*Dd + j];
  h0[(size_t)n*Dd + j] = s;
}

// agg[dst] += h[src], float4 per 32 threads/edge
__global__ void k_scatter(float* __restrict__ agg, const float* __restrict__ h,
                          const int* __restrict__ src, const int* __restrict__ dst){
  int idx = blockIdx.x*blockDim.x + threadIdx.x;
  if (idx >= Ec*32) return;
  int e = idx >> 5, c = (idx & 31) << 2;
  int s = src[e], d = dst[e];
  const float4 v = *(const float4*)(h + (size_t)s*Dd + c);
  float* a = agg + (size_t)d*Dd + c;
  atomicAdd(a+0, v.x); atomicAdd(a+1, v.y); atomicAdd(a+2, v.z); atomicAdd(a+3, v.w);
}

// out = relu(agg@W + b) + relu(h@Wr + br); rows staged in LDS
__global__ void k_gcn(float* __restrict__ out, const float* __restrict__ agg, const float* __restrict__ h,
                      const float* __restrict__ W, const float* __restrict__ bvec,
                      const float* __restrict__ Wr, const float* __restrict__ br){
  int n = blockIdx.x, j = threadIdx.x;
  __shared__ float ar[Dd], hr[Dd];
  ar[j] = agg[(size_t)n*Dd+j]; hr[j] = h[(size_t)n*Dd+j];
  __syncthreads();
  float s1=0.f, s2=0.f;
  #pragma unroll 8
  for (int k=0;k<Dd;k++){ s1 += ar[k]*W[(size_t)k*Dd+j]; s2 += hr[k]*Wr[(size_t)k*Dd+j]; }
  s1 += bvec[j]; s2 += br[j];
  out[(size_t)n*Dd+j] = fmaxf(s1,0.f) + fmaxf(s2,0.f);
}

// ---------------- ProteinCNN ----------------
__global__ void k_embed(float* __restrict__ x, const int* __restrict__ vp, const float* __restrict__ emb){
  int t = blockIdx.x*blockDim.x + threadIdx.x;
  int d = blockIdx.y, b = blockIdx.z;
  if (t >= LPc) return;
  int tok = vp[b*LPc + t];
  x[((size_t)b*Dd + d)*LPc + t] = emb[(size_t)tok*Dd + d];
}

// weights in LDS; coalesced x reads over t
__global__ void k_conv(float* __restrict__ y, const float* __restrict__ x, const float* __restrict__ w,
                       const float* __restrict__ cb, int Lin, int Lout, int KW, int cbo){
  int o = blockIdx.y, b = blockIdx.z;
  int t = blockIdx.x*blockDim.x + threadIdx.x;
  extern __shared__ float wsm[];
  for (int i = threadIdx.x; i < Dd*KW; i += blockDim.x) wsm[i] = w[(size_t)o*Dd*KW + i];
  __syncthreads();
  if (t >= Lout) return;
  const float* xb_ = x + (size_t)b*Dd*Lin;
  float s = cb[cbo + o];
  for (int i=0;i<Dd;i++){
    const float* xi = xb_ + (size_t)i*Lin + t;
    const float* wi = wsm + i*KW;
    #pragma unroll 3
    for (int k=0;k<KW;k++) s += xi[k]*wi[k];
  }
  y[((size_t)b*Dd+o)*Lout + t] = fmaxf(s, 0.f);
}

__global__ void k_bnc_stats(float* __restrict__ mean, float* __restrict__ rstd,
                            const float* __restrict__ y, int Lout){
  int c = blockIdx.x;
  float s=0.f, ss=0.f;
  int cnt = Bc*Lout;
  for (int i = threadIdx.x; i < cnt; i += blockDim.x){
    int b = i / Lout, t = i - b*Lout;
    float v = y[((size_t)b*Dd+c)*Lout + t];
    s += v; ss += v*v;
  }
  __shared__ float rs[256], rss[256];
  rs[threadIdx.x]=s; rss[threadIdx.x]=ss; __syncthreads();
  for (int st=128; st>0; st>>=1){
    if (threadIdx.x<st){ rs[threadIdx.x]+=rs[threadIdx.x+st]; rss[threadIdx.x]+=rss[threadIdx.x+st]; }
    __syncthreads();
  }
  if (threadIdx.x==0){
    float m = rs[0]/cnt; float v = rss[0]/cnt - m*m; if (v<0.f) v=0.f;
    mean[c]=m; rstd[c]=rsqrtf(v+1e-5f);
  }
}

__global__ void k_bnc_apply(float* __restrict__ y, const float* __restrict__ mean, const float* __restrict__ rstd,
                            const float* __restrict__ g, const float* __restrict__ bb, int Lout, int go){
  size_t idx = (size_t)blockIdx.x*blockDim.x + threadIdx.x;
  size_t tot = (size_t)Bc*Dd*Lout;
  if (idx >= tot) return;
  int c = (int)((idx / Lout) & (Dd-1));
  y[idx] = (y[idx]-mean[c])*rstd[c]*g[go+c] + bb[go+c];
}

// ---------------- BAN via Gram factorization (algebra verified r2-r5 equivalence) ----------------
// qc[b,tt,j] = relu( sum_d cnnOut[b,d,t0c+tt]*Wq[d,j] + bq[j] )
__global__ void k_qgemm_chunk(float* __restrict__ qc, const float* __restrict__ x,
                              const float* __restrict__ W, const float* __restrict__ bias, int t0c){
  int tt = blockIdx.y, b = blockIdx.z;
  int j = blockIdx.x*blockDim.x + threadIdx.x;
  __shared__ float xr[Dd];
  if (threadIdx.x < Dd) xr[threadIdx.x] = x[((size_t)b*Dd+threadIdx.x)*LQ + t0c + tt];
  __syncthreads();
  float s = bias[j];
  #pragma unroll 8
  for (int d=0; d<Dd; d++) s += xr[d]*W[(size_t)d*HKc + j];
  qc[((size_t)b*CHT + tt)*HKc + j] = fmaxf(s, 0.f);
}

// Sq[b,j] += sum_{tt<Tc} qc[b,tt,j]
__global__ void k_colsum_acc(float* __restrict__ S, const float* __restrict__ X, int Tc){
  int j = blockIdx.x*blockDim.x + threadIdx.x;
  int b = blockIdx.y;
  if (j >= HKc) return;
  const float* p = X + (size_t)b*CHT*HKc + j;
  float s=0.f;
  for (int t=0;t<Tc;t++) s += p[(size_t)t*HKc];
  S[b*HKc + j] += s;
}

// Gq[b] += qc[b]^T qc[b], 64x64 tiles, 4x4/thread
__global__ void k_gram_acc(float* __restrict__ G, const float* __restrict__ X, int Tc){
  int b = blockIdx.z;
  int r0 = blockIdx.y*64, c0 = blockIdx.x*64;
  const float* Xb = X + (size_t)b*CHT*HKc;
  float* Gb = G + (size_t)b*HKc*HKc;
  __shared__ float As[16][64], Bs[16][64];
  int tid = threadIdx.x;
  int tx = tid & 15, ty = tid >> 4;
  int ldr = tid >> 4, ldc = (tid & 15)*4;
  float acc[4][4] = {};
  for (int t0=0; t0<Tc; t0+=16){
    float4 av = make_float4(0.f,0.f,0.f,0.f), bv4 = make_float4(0.f,0.f,0.f,0.f);
    if (t0+ldr < Tc){
      const float* row = Xb + (size_t)(t0+ldr)*HKc;
      av  = *(const float4*)(row + r0 + ldc);
      bv4 = *(const float4*)(row + c0 + ldc);
    }
    *(float4*)&As[ldr][ldc] = av;
    *(float4*)&Bs[ldr][ldc] = bv4;
    __syncthreads();
    #pragma unroll
    for (int tt=0; tt<16; tt++){
      float a[4], bb[4];
      *(float4*)a  = *(const float4*)&As[tt][ty*4];
      *(float4*)bb = *(const float4*)&Bs[tt][tx*4];
      #pragma unroll
      for (int i=0;i<4;i++)
        #pragma unroll
        for (int j=0;j<4;j++) acc[i][j] += a[i]*bb[j];
    }
    __syncthreads();
  }
  for (int i=0;i<4;i++){
    int r = r0 + ty*4 + i;
    float* gp = Gb + (size_t)r*HKc + c0 + tx*4;
    float4 old = *(const float4*)gp;
    old.x += acc[i][0]; old.y += acc[i][1]; old.z += acc[i][2]; old.w += acc[i][3];
    *(float4*)gp = old;
  }
}

// v[r,j] = relu( sum_d gout[(rbase+r),d]*Wv[d,j] + bv[j] )
__global__ void k_vgemm(float* __restrict__ v, const float* __restrict__ vd,
                        const float* __restrict__ W, const float* __restrict__ bias, int rbase){
  int r = blockIdx.y;
  int j = blockIdx.x*blockDim.x + threadIdx.x;
  __shared__ float xr[Dd];
  if (threadIdx.x < Dd) xr[threadIdx.x] = vd[(size_t)(rbase+r)*Dd + threadIdx.x];
  __syncthreads();
  float s = bias[j];
  #pragma unroll 8
  for (int d=0; d<Dd; d++) s += xr[d]*W[(size_t)d*HKc + j];
  v[(size_t)r*HKc + j] = fmaxf(s,0.f);
}

// Sv[(bbase+bl),j] = sum_t V[bl*290+t, j]
__global__ void k_colsum_v(float* __restrict__ S, const float* __restrict__ X, int bbase){
  int j = blockIdx.x*blockDim.x + threadIdx.x;
  int bl = blockIdx.y;
  if (j >= HKc) return;
  const float* p = X + (size_t)bl*NPGc*HKc + j;
  float s=0.f;
  for (int t=0;t<NPGc;t++) s += p[(size_t)t*HKc];
  S[(bbase+bl)*HKc + j] = s;
}

// Fused: Gv tile (V^T V) weighted by Hsum[c]*Gq[bg,r,c], row-reduce -> atomicAdd f[bg,r]
__global__ void k_gramf(float* __restrict__ f, const float* __restrict__ V,
                        const float* __restrict__ Gq_, const float* __restrict__ hm, int bbase){
  int bl = blockIdx.z, bg = bbase + bl;
  int r0 = blockIdx.y*64, c0 = blockIdx.x*64;
  const float* Vb = V + (size_t)bl*NPGc*HKc;
  __shared__ float As[16][64], Bs[16][64];
  __shared__ float wsum[64];
  int tid = threadIdx.x;
  int tx = tid & 15, ty = tid >> 4;
  int ldr = tid >> 4, ldc = (tid & 15)*4;
  if (tid < 64) wsum[tid] = hm[c0+tid] + hm[HKc + c0 + tid];
  float acc[4][4] = {};
  for (int t0=0; t0<NPGc; t0+=16){
    float4 av = make_float4(0.f,0.f,0.f,0.f), bv4 = make_float4(0.f,0.f,0.f,0.f);
    if (t0+ldr < NPGc){
      const float* row = Vb + (size_t)(t0+ldr)*HKc;
      av  = *(const float4*)(row + r0 + ldc);
      bv4 = *(const float4*)(row + c0 + ldc);
    }
    *(float4*)&As[ldr][ldc] = av;
    *(float4*)&Bs[ldr][ldc] = bv4;
    __syncthreads();
    #pragma unroll
    for (int tt=0; tt<16; tt++){
      float a[4], bb[4];
      *(float4*)a  = *(const float4*)&As[tt][ty*4];
      *(float4*)bb = *(const float4*)&Bs[tt][tx*4];
      #pragma unroll
      for (int i=0;i<4;i++)
        #pragma unroll
        for (int j=0;j<4;j++) acc[i][j] += a[i]*bb[j];
    }
    __syncthreads();
  }
  const float* gqb = Gq_ + (size_t)bg*HKc*HKc;
  float w[4];
  #pragma unroll
  for (int j=0;j<4;j++) w[j] = wsum[tx*4+j];
  #pragma unroll
  for (int i=0;i<4;i++){
    int r = r0 + ty*4 + i;
    const float4 g4 = *(const float4*)(gqb + (size_t)r*HKc + c0 + tx*4);
    float s = acc[i][0]*w[0]*g4.x + acc[i][1]*w[1]*g4.y
            + acc[i][2]*w[2]*g4.z + acc[i][3]*w[3]*g4.w;
    s += __shfl_xor(s, 1); s += __shfl_xor(s, 2);
    s += __shfl_xor(s, 4); s += __shfl_xor(s, 8);
    if (tx==0) atomicAdd(&f[bg*HKc + r], s);
  }
}

// fp[b,c] = sum_{r<3} ( f[b,3c+r] + Hbsum*Sv*Sq )
__global__ void k_pool(float* __restrict__ fp, const float* __restrict__ f,
                       const float* __restrict__ Sv, const float* __restrict__ Sq,
                       const float* __restrict__ hb){
  int idx = blockIdx.x*blockDim.x + threadIdx.x;
  if (idx >= Bc*256) return;
  int b = idx >> 8, c = idx & 255;
  float hbs = hb[0] + hb[1];
  float s = 0.f;
  #pragma unroll
  for (int r=0;r<3;r++){
    int k = c*3 + r;
    s += f[b*HKc + k] + hbs*Sv[b*HKc + k]*Sq[b*HKc + k];
  }
  fp[idx] = s;
}

// ---------------- tail ----------------
__global__ void k_bnfeat(float* __restrict__ y, const float* __restrict__ x, const float* __restrict__ g,
                         const float* __restrict__ bb, int C){
  int c = blockIdx.x; int b = threadIdx.x; // 32 threads
  __shared__ float buf[32];
  __shared__ float mv[2];
  float v = x[b*C + c];
  buf[b] = v;
  __syncthreads();
  if (b == 0){
    float s = 0.f;
    for (int i=0;i<32;i++) s += buf[i];
    float m = s/32.f;
    float vs = 0.f;
    for (int i=0;i<32;i++){ float d = buf[i]-m; vs += d*d; }
    mv[0] = m; mv[1] = vs/32.f;
  }
  __syncthreads();
  y[b*C + c] = (v - mv[0])*rsqrtf(mv[1]+1e-5f)*g[c] + bb[c];
}

__global__ void k_mlp(float* __restrict__ out, const float* __restrict__ in, const float* __restrict__ W,
                      const float* __restrict__ bias, int K, int Nc, int doRelu){
  int b = blockIdx.y;
  int j = blockIdx.x*blockDim.x + threadIdx.x;
  __shared__ float xr[512];
  for (int k=threadIdx.x; k<K; k+=blockDim.x) xr[k] = in[b*K+k];
  __syncthreads();
  if (j >= Nc) return;
  float s = bias[j];
  for (int k=0;k<K;k++) s += xr[k]*W[(size_t)k*Nc + j];
  if (doRelu) s = fmaxf(s, 0.f);
  out[b*Nc + j] = s;
}

__global__ void k_score(float* __restrict__ sc, const float* __restrict__ h, const float* __restrict__ w,
                        const float* __restrict__ bb){
  int b = threadIdx.x; if (b>=32) return;
  float s = bb[0];
  for (int k=0;k<Dd;k++) s += h[b*Dd+k]*w[k];
  sc[b] = s;
}

// FP32 output: out[4b+0..3] = score_o[b], s1[b], s2[b], loss
__global__ void k_out(float* __restrict__ out, const float* __restrict__ scores){
  int t = threadIdx.x;
  __shared__ float loss_s;
  if (t == 0){
    float sn1[32], sn2[32];
    for (int i=0;i<32;i++){
      float a = scores[32+i]; sn1[i] = a / fmaxf(fabsf(a), 1e-12f);
      float c = scores[64+i]; sn2[i] = c / fmaxf(fabsf(c), 1e-12f);
    }
    float acc = 0.f;
    for (int i=0;i<32;i++){
      float mx = -1e30f;
      for (int j=0;j<32;j++) mx = fmaxf(mx, sn1[i]*sn2[j]);
      float se = 0.f;
      for (int j=0;j<32;j++) se += expf(sn1[i]*sn2[j]-mx);
      acc += sn1[i]*sn2[i] - (mx + logf(se));
    }
    loss_s = -acc/32.f;
  }
  __syncthreads();
  out[t*4+0] = scores[t];
  out[t*4+1] = scores[32+t];
  out[t*4+2] = scores[64+t];
  out[t*4+3] = loss_s;
}

extern "C" void kernel_launch(void* const* d_in, const int* in_sizes, int n_in,
                              void* d_out, int out_size, void* d_ws, size_t ws_size,
                              hipStream_t stream){
  static const int exp_sizes[38] = {
    Nn*INFc, Ec, Ec, Bc*LPc, INFc*Dd,
    9*Dd*Dd, 9*Dd, 9*Dd*Dd, 9*Dd,
    26*Dd, Dd*Dd*3, Dd*Dd*6, Dd*Dd*9, 3*Dd, 3*Dd, 3*Dd,
    Dd*HKc, HKc, Dd*HKc, HKc, 2*HKc, 2, 256, 256,
    256*512, 512, 512*512, 512, 512*128, 128, 128, 1,
    512, 512, 512, 512, 128, 128 };
  if (n_in != 38){ k_sentinel<<<1,128,0,stream>>>((float*)d_out, 2000.f + n_in); return; }
  for (int i=0;i<38;i++){
    if (in_sizes[i] != exp_sizes[i]){
      k_sentinel<<<1,128,0,stream>>>((float*)d_out, 1000.f + i); return;
    }
  }

  const float* node_h=(const float*)d_in[0];
  const int*  esrc  =(const int*)d_in[1];
  const int*  edst  =(const int*)d_in[2];
  const int*  vp    =(const int*)d_in[3];
  const float* W_init=(const float*)d_in[4];
  const float* gcn_W =(const float*)d_in[5];
  const float* gcn_b =(const float*)d_in[6];
  const float* gcn_Wr=(const float*)d_in[7];
  const float* gcn_br=(const float*)d_in[8];
  const float* emb   =(const float*)d_in[9];
  const float* c1w=(const float*)d_in[10];
  const float* c2w=(const float*)d_in[11];
  const float* c3w=(const float*)d_in[12];
  const float* cbv=(const float*)d_in[13];
  const float* bng=(const float*)d_in[14];
  const float* bnb=(const float*)d_in[15];
  const float* Wv =(const float*)d_in[16];
  const float* bvv=(const float*)d_in[17];
  const float* Wq =(const float*)d_in[18];
  const float* bq =(const float*)d_in[19];
  const float* hmat =(const float*)d_in[20];
  const float* hbias=(const float*)d_in[21];
  const float* bang =(const float*)d_in[22];
  const float* banb =(const float*)d_in[23];
  const float* mw1=(const float*)d_in[24]; const float* mb1=(const float*)d_in[25];
  const float* mw2=(const float*)d_in[26]; const float* mb2=(const float*)d_in[27];
  const float* mw3=(const float*)d_in[28]; const float* mb3=(const float*)d_in[29];
  const float* mw4=(const float*)d_in[30]; const float* mb4=(const float*)d_in[31];
  const float* g1=(const float*)d_in[32]; const float* bb1=(const float*)d_in[33];
  const float* g2=(const float*)d_in[34]; const float* bb2=(const float*)d_in[35];
  const float* g3=(const float*)d_in[36]; const float* bb3=(const float*)d_in[37];

  float* ws = (float*)d_ws;
  size_t off = 0;
  auto alloc = [&](size_t n){ float* p = ws + off; off += n; return p; };

  const size_t NDsz = (size_t)Nn*Dd;         // 1,187,840
  const size_t CNNB = (size_t)Bc*Dd*LPc;     // 3,686,400
  const size_t ARENA = 2*CNNB;               // 7,372,800

  // smalls
  float* Sq  = alloc((size_t)Bc*HKc);
  float* Sv  = alloc((size_t)Bc*HKc);
  float* fbuf= alloc((size_t)Bc*HKc);
  float* fpool=alloc((size_t)Bc*256);
  float* hh1 = alloc((size_t)Bc*512);
  float* hh2 = alloc((size_t)Bc*512);
  float* hh3 = alloc((size_t)Bc*128);
  float* sc  = alloc(96);
  float* bnm = alloc(128);
  float* bnr = alloc(128);
  // persistent big: fp32 Gq
  float* Gq  = alloc((size_t)Bc*HKc*HKc);    // 18,874,368
  // phase-overlapped arena
  float* arena = alloc(ARENA);
  // total ≈ 26.37M floats ≈ 105.5 MiB (same footprint as proven-safe round 3)

  // phase views
  float* cnnA = arena;                // CNN final output lands here (885-wide)
  float* cnnB = arena + CNNB;
  float* qc   = arena + CNNB;         // 32*128*768 = 3,145,728 < CNNB
  float* A0 = arena;                  // GCN/view phase
  float* A1 = arena + NDsz;
  float* A2t= arena + 2*NDsz;
  float* A3 = arena + 3*NDsz;
  float* vbuf = arena + NDsz;         // 16*290*768 = 3,563,520 (ends at 4.75M)

  // ---- ProteinCNN (ping-pong; final output in cnnA) ----
  k_embed<<<dim3((LPc+127)/128, Dd, Bc),128,0,stream>>>(cnnB, vp, emb);
  k_conv<<<dim3((898+127)/128,Dd,Bc),128,Dd*3*sizeof(float),stream>>>(cnnA, cnnB, c1w, cbv, 900, 898, 3, 0);
  k_bnc_stats<<<Dd,256,0,stream>>>(bnm,bnr,cnnA,898);
  { size_t t0=(size_t)Bc*Dd*898;
    k_bnc_apply<<<(unsigned)((t0+255)/256),256,0,stream>>>(cnnA,bnm,bnr,bng,bnb,898,0); }
  k_conv<<<dim3((893+127)/128,Dd,Bc),128,Dd*6*sizeof(float),stream>>>(cnnB, cnnA, c2w, cbv, 898, 893, 6, 128);
  k_bnc_stats<<<Dd,256,0,stream>>>(bnm,bnr,cnnB,893);
  { size_t t1=(size_t)Bc*Dd*893;
    k_bnc_apply<<<(unsigned)((t1+255)/256),256,0,stream>>>(cnnB,bnm,bnr,bng,bnb,893,128); }
  k_conv<<<dim3((885+127)/128,Dd,Bc),128,Dd*9*sizeof(float),stream>>>(cnnA, cnnB, c3w, cbv, 893, 885, 9, 256);
  k_bnc_stats<<<Dd,256,0,stream>>>(bnm,bnr,cnnA,885);
  { size_t t2=(size_t)Bc*Dd*885;
    k_bnc_apply<<<(unsigned)((t2+255)/256),256,0,stream>>>(cnnA,bnm,bnr,bng,bnb,885,256); }

  // ---- q branch: chunked fp32 Gq/Sq accumulation ----
  hipMemsetAsync(Gq, 0, (size_t)Bc*HKc*HKc*sizeof(float), stream);
  hipMemsetAsync(Sq, 0, (size_t)Bc*HKc*sizeof(float), stream);
  for (int t0c = 0; t0c < LQ; t0c += CHT){
    int Tc = LQ - t0c; if (Tc > CHT) Tc = CHT;
    k_qgemm_chunk<<<dim3(3,Tc,Bc),256,0,stream>>>(qc, cnnA, Wq, bq, t0c);
    k_colsum_acc<<<dim3(3,Bc),256,0,stream>>>(Sq, qc, Tc);
    k_gram_acc<<<dim3(12,12,Bc),256,0,stream>>>(Gq, qc, Tc);
  }

  // ---- three GCN branches + Gram-fused BAN + MLPs ----
  for (int g=0; g<3; g++){
    k_h0<<<Nn,Dd,0,stream>>>(A1, node_h, W_init);
    // l=0: A1 -> A3
    hipMemsetAsync(A2t, 0, NDsz*sizeof(float), stream);
    k_scatter<<<(Ec*32+255)/256,256,0,stream>>>(A2t, A1, esrc, edst);
    { int wo=g*3+0;
      k_gcn<<<Nn,Dd,0,stream>>>(A3, A2t, A1, gcn_W+(size_t)wo*Dd*Dd, gcn_b+(size_t)wo*Dd,
                                gcn_Wr+(size_t)wo*Dd*Dd, gcn_br+(size_t)wo*Dd); }
    // l=1: A3 -> A1
    hipMemsetAsync(A2t, 0, NDsz*sizeof(float), stream);
    k_scatter<<<(Ec*32+255)/256,256,0,stream>>>(A2t, A3, esrc, edst);
    { int wo=g*3+1;
      k_gcn<<<Nn,Dd,0,stream>>>(A1, A2t, A3, gcn_W+(size_t)wo*Dd*Dd, gcn_b+(size_t)wo*Dd,
                                gcn_Wr+(size_t)wo*Dd*Dd, gcn_br+(size_t)wo*Dd); }
    // l=2: A1 -> A0
    hipMemsetAsync(A2t, 0, NDsz*sizeof(float), stream);
    k_scatter<<<(Ec*32+255)/256,256,0,stream>>>(A2t, A1, esrc, edst);
    { int wo=g*3+2;
      k_gcn<<<Nn,Dd,0,stream>>>(A0, A2t, A1, gcn_W+(size_t)wo*Dd*Dd, gcn_b+(size_t)wo*Dd,
                                gcn_Wr+(size_t)wo*Dd*Dd, gcn_br+(size_t)wo*Dd); }

    // BAN view in two half-batches of 16 graphs (Gv fused away)
    hipMemsetAsync(fbuf, 0, (size_t)Bc*HKc*sizeof(float), stream);
    for (int p=0; p<2; p++){
      int bbase = p*16;
      k_vgemm<<<dim3(3,16*NPGc),256,0,stream>>>(vbuf, A0, Wv, bvv, bbase*NPGc);
      k_colsum_v<<<dim3(3,16),256,0,stream>>>(Sv, vbuf, bbase);
      k_gramf<<<dim3(12,12,16),256,0,stream>>>(fbuf, vbuf, Gq, hmat, bbase);
    }
    k_pool<<<(Bc*256+255)/256,256,0,stream>>>(fpool, fbuf, Sv, Sq, hbias);
    k_bnfeat<<<256,32,0,stream>>>(fpool, fpool, bang, banb, 256);
    k_mlp<<<dim3(2,Bc),256,0,stream>>>(hh1, fpool, mw1, mb1, 256, 512, 1);
    k_bnfeat<<<512,32,0,stream>>>(hh1,hh1,g1,bb1,512);
    k_mlp<<<dim3(2,Bc),256,0,stream>>>(hh2, hh1, mw2, mb2, 512, 512, 1);
    k_bnfeat<<<512,32,0,stream>>>(hh2,hh2,g2,bb2,512);
    k_mlp<<<dim3(1,Bc),256,0,stream>>>(hh3, hh2, mw3, mb3, 512, 128, 1);
    k_bnfeat<<<128,32,0,stream>>>(hh3,hh3,g3,bb3,128);
    k_score<<<1,32,0,stream>>>(sc + 32*g, hh3, mw4, mb4);
  }

  k_out<<<1,32,0,stream>>>((float*)d_out, sc);
}

// Round 10
// 3365.789 us; speedup vs baseline: 24.0816x; 1.6854x over previous
//
#include <hip/hip_runtime.h>
#include <hip/hip_bf16.h>

#define Bc 32
#define NPGc 290
#define Nn 9280
#define Ec 74240
#define LPc 900
#define INFc 75
#define Dd 128
#define HKc 768
#define LQ 885
#define CHT 128   // q-chunk timesteps
#define CT 64     // conv t-tile

__global__ void k_sentinel(float* out, float val){
  int t = threadIdx.x;
  if (t < 128) out[t] = val;
}

// ---------------- GCN ----------------
__global__ void k_h0(float* __restrict__ h0, const float* __restrict__ nh, const float* __restrict__ Wi){
  int n = blockIdx.x, j = threadIdx.x;
  __shared__ float arow[INFc];
  if (j < INFc) arow[j] = nh[(size_t)n*INFc + j];
  __syncthreads();
  float s = 0.f;
  #pragma unroll 5
  for (int k=0;k<INFc;k++) s += arow[k]*Wi[(size_t)k*Dd + j];
  h0[(size_t)n*Dd + j] = s;
}

// dense adjacency: A[b][dst_local][src_local] += 1  (edges fixed -> built once)
__global__ void k_build_adj(float* __restrict__ A, const int* __restrict__ src, const int* __restrict__ dst){
  int e = blockIdx.x*blockDim.x + threadIdx.x;
  if (e >= Ec) return;
  int s = src[e], d = dst[e];
  int b = d / NPGc;
  int dl = d - b*NPGc, sl = s - b*NPGc;
  atomicAdd(&A[((size_t)b*NPGc + dl)*NPGc + sl], 1.f);
}

// agg[b*290+i, c] = sum_j A[b,i,j] * h[b*290+j, c]; 8 i-rows per block, 128 threads (c)
__global__ void k_aggmm(float* __restrict__ agg, const float* __restrict__ A, const float* __restrict__ h){
  int b = blockIdx.y;
  int i0 = blockIdx.x*8;
  int c = threadIdx.x;
  __shared__ float arow[8][NPGc];
  for (int idx = threadIdx.x; idx < 8*NPGc; idx += 128){
    int r = idx / NPGc, j = idx - r*NPGc;
    arow[r][j] = (i0 + r < NPGc) ? A[((size_t)b*NPGc + i0 + r)*NPGc + j] : 0.f;
  }
  __syncthreads();
  float acc[8] = {};
  const float* hb = h + (size_t)b*NPGc*Dd + c;
  for (int j = 0; j < NPGc; j++){
    float hv = hb[(size_t)j*Dd];
    #pragma unroll
    for (int r=0;r<8;r++) acc[r] += arow[r][j]*hv;
  }
  int nr = NPGc - i0; if (nr > 8) nr = 8;
  for (int r=0;r<nr;r++)
    agg[((size_t)b*NPGc + i0 + r)*Dd + c] = acc[r];
}

// 8 nodes/block: out = relu(agg@W+b) + relu(h@Wr+br); 16 FMA per 2 global loads
__global__ void k_gcn8(float* __restrict__ out, const float* __restrict__ agg, const float* __restrict__ h,
                       const float* __restrict__ W, const float* __restrict__ bvec,
                       const float* __restrict__ Wr, const float* __restrict__ br){
  int n0 = blockIdx.x*8;
  int j = threadIdx.x;
  __shared__ float ar[8][Dd], hr[8][Dd];
  for (int idx = threadIdx.x; idx < 8*Dd; idx += 128){
    int r = idx >> 7, k = idx & 127;
    ar[r][k] = agg[((size_t)(n0+r))*Dd + k];
    hr[r][k] = h[((size_t)(n0+r))*Dd + k];
  }
  __syncthreads();
  float s1[8], s2[8];
  float bj = bvec[j], brj = br[j];
  #pragma unroll
  for (int r=0;r<8;r++){ s1[r]=bj; s2[r]=brj; }
  for (int k=0;k<Dd;k++){
    float wk = W[(size_t)k*Dd+j], wrk = Wr[(size_t)k*Dd+j];
    #pragma unroll
    for (int r=0;r<8;r++){ s1[r] += ar[r][k]*wk; s2[r] += hr[r][k]*wrk; }
  }
  #pragma unroll
  for (int r=0;r<8;r++)
    out[((size_t)(n0+r))*Dd + j] = fmaxf(s1[r],0.f) + fmaxf(s2[r],0.f);
}

// ---------------- ProteinCNN ----------------
__global__ void k_embed(float* __restrict__ x, const int* __restrict__ vp, const float* __restrict__ emb){
  int t = blockIdx.x*blockDim.x + threadIdx.x;
  int d = blockIdx.y, b = blockIdx.z;
  if (t >= LPc) return;
  int tok = vp[b*LPc + t];
  x[((size_t)b*Dd + d)*LPc + t] = emb[(size_t)tok*Dd + d];
}

// LDS-tiled conv: block=(t-tile, b), all 128 o; window register-cached
template<int KW>
__global__ void k_conv_t(float* __restrict__ y, const float* __restrict__ x, const float* __restrict__ w,
                         const float* __restrict__ cb, int Lin, int Lout, int cbo){
  int b = blockIdx.y;
  int t0 = blockIdx.x*CT;
  const int W2 = CT + KW - 1;
  extern __shared__ float xs[];  // [128][W2]
  for (int idx = threadIdx.x; idx < Dd*W2; idx += 256){
    int i = idx / W2, tt = idx - i*W2;
    int t = t0 + tt;
    xs[i*W2 + tt] = (t < Lin) ? x[((size_t)b*Dd + i)*Lin + t] : 0.f;
  }
  __syncthreads();
  int o = threadIdx.x >> 1;
  int tb = (threadIdx.x & 1)*32;
  float acc[32];
  float bias = cb[cbo+o];
  #pragma unroll
  for (int t=0;t<32;t++) acc[t]=bias;
  for (int i=0;i<Dd;i++){
    const float* xrow = xs + i*W2 + tb;
    float xr[32+KW-1];
    #pragma unroll
    for (int t=0;t<32+KW-1;t++) xr[t] = xrow[t];
    const float* wp = w + ((size_t)o*Dd + i)*KW;
    #pragma unroll
    for (int k=0;k<KW;k++){
      float wk = wp[k];
      #pragma unroll
      for (int t=0;t<32;t++) acc[t] += xr[t+k]*wk;
    }
  }
  #pragma unroll
  for (int t=0;t<32;t++){
    int tt = t0 + tb + t;
    if (tt < Lout) y[((size_t)b*Dd+o)*Lout + tt] = fmaxf(acc[t],0.f);
  }
}

__global__ void k_bnc_stats(float* __restrict__ mean, float* __restrict__ rstd,
                            const float* __restrict__ y, int Lout){
  int c = blockIdx.x;
  float s=0.f, ss=0.f;
  int cnt = Bc*Lout;
  for (int i = threadIdx.x; i < cnt; i += blockDim.x){
    int b = i / Lout, t = i - b*Lout;
    float v = y[((size_t)b*Dd+c)*Lout + t];
    s += v; ss += v*v;
  }
  __shared__ float rs[256], rss[256];
  rs[threadIdx.x]=s; rss[threadIdx.x]=ss; __syncthreads();
  for (int st=128; st>0; st>>=1){
    if (threadIdx.x<st){ rs[threadIdx.x]+=rs[threadIdx.x+st]; rss[threadIdx.x]+=rss[threadIdx.x+st]; }
    __syncthreads();
  }
  if (threadIdx.x==0){
    float m = rs[0]/cnt; float v = rss[0]/cnt - m*m; if (v<0.f) v=0.f;
    mean[c]=m; rstd[c]=rsqrtf(v+1e-5f);
  }
}

__global__ void k_bnc_apply(float* __restrict__ y, const float* __restrict__ mean, const float* __restrict__ rstd,
                            const float* __restrict__ g, const float* __restrict__ bb, int Lout, int go){
  size_t idx = (size_t)blockIdx.x*blockDim.x + threadIdx.x;
  size_t tot = (size_t)Bc*Dd*Lout;
  if (idx >= tot) return;
  int c = (int)((idx / Lout) & (Dd-1));
  y[idx] = (y[idx]-mean[c])*rstd[c]*g[go+c] + bb[go+c];
}

// ---------------- BAN via Gram factorization ----------------
// qc[b,m,j] = relu( X^T W + bias ); tiled GEMM M=Tc, N=768, K=128
__global__ void k_qgemm_tile(float* __restrict__ qc, const float* __restrict__ x,
                             const float* __restrict__ W, const float* __restrict__ bias,
                             int t0c, int Tc){
  int b = blockIdx.z;
  int m0 = blockIdx.y*64;
  int n0 = blockIdx.x*64;
  __shared__ float As[16][64], Bs[16][64];
  int tid = threadIdx.x;
  int tx = tid & 15, ty = tid >> 4;
  int ldr = tid >> 4, ldc = (tid & 15)*4;
  float acc[4][4] = {};
  for (int k0 = 0; k0 < Dd; k0 += 16){
    const float* xrow = x + ((size_t)b*Dd + k0 + ldr)*LQ + t0c + m0 + ldc;
    int mb = m0 + ldc;
    float4 a4;
    a4.x = (mb+0 < Tc) ? xrow[0] : 0.f;
    a4.y = (mb+1 < Tc) ? xrow[1] : 0.f;
    a4.z = (mb+2 < Tc) ? xrow[2] : 0.f;
    a4.w = (mb+3 < Tc) ? xrow[3] : 0.f;
    *(float4*)&As[ldr][ldc] = a4;
    *(float4*)&Bs[ldr][ldc] = *(const float4*)(W + (size_t)(k0+ldr)*HKc + n0 + ldc);
    __syncthreads();
    #pragma unroll
    for (int kk=0; kk<16; kk++){
      float a[4], bb[4];
      *(float4*)a  = *(const float4*)&As[kk][ty*4];
      *(float4*)bb = *(const float4*)&Bs[kk][tx*4];
      #pragma unroll
      for (int i=0;i<4;i++)
        #pragma unroll
        for (int j=0;j<4;j++) acc[i][j] += a[i]*bb[j];
    }
    __syncthreads();
  }
  #pragma unroll
  for (int i=0;i<4;i++){
    int m = m0 + ty*4 + i;
    if (m >= Tc) continue;
    int n = n0 + tx*4;
    float4 o;
    o.x = fmaxf(acc[i][0] + bias[n+0], 0.f);
    o.y = fmaxf(acc[i][1] + bias[n+1], 0.f);
    o.z = fmaxf(acc[i][2] + bias[n+2], 0.f);
    o.w = fmaxf(acc[i][3] + bias[n+3], 0.f);
    *(float4*)(qc + ((size_t)b*CHT + m)*HKc + n) = o;
  }
}

__global__ void k_colsum_acc(float* __restrict__ S, const float* __restrict__ X, int Tc){
  int j = blockIdx.x*blockDim.x + threadIdx.x;
  int b = blockIdx.y;
  if (j >= HKc) return;
  const float* p = X + (size_t)b*CHT*HKc + j;
  float s=0.f;
  for (int t=0;t<Tc;t++) s += p[(size_t)t*HKc];
  S[b*HKc + j] += s;
}

__global__ void k_gram_acc(float* __restrict__ G, const float* __restrict__ X, int Tc){
  int b = blockIdx.z;
  int r0 = blockIdx.y*64, c0 = blockIdx.x*64;
  const float* Xb = X + (size_t)b*CHT*HKc;
  float* Gb = G + (size_t)b*HKc*HKc;
  __shared__ float As[16][64], Bs[16][64];
  int tid = threadIdx.x;
  int tx = tid & 15, ty = tid >> 4;
  int ldr = tid >> 4, ldc = (tid & 15)*4;
  float acc[4][4] = {};
  for (int t0=0; t0<Tc; t0+=16){
    float4 av = make_float4(0.f,0.f,0.f,0.f), bv4 = make_float4(0.f,0.f,0.f,0.f);
    if (t0+ldr < Tc){
      const float* row = Xb + (size_t)(t0+ldr)*HKc;
      av  = *(const float4*)(row + r0 + ldc);
      bv4 = *(const float4*)(row + c0 + ldc);
    }
    *(float4*)&As[ldr][ldc] = av;
    *(float4*)&Bs[ldr][ldc] = bv4;
    __syncthreads();
    #pragma unroll
    for (int tt=0; tt<16; tt++){
      float a[4], bb[4];
      *(float4*)a  = *(const float4*)&As[tt][ty*4];
      *(float4*)bb = *(const float4*)&Bs[tt][tx*4];
      #pragma unroll
      for (int i=0;i<4;i++)
        #pragma unroll
        for (int j=0;j<4;j++) acc[i][j] += a[i]*bb[j];
    }
    __syncthreads();
  }
  for (int i=0;i<4;i++){
    int r = r0 + ty*4 + i;
    float* gp = Gb + (size_t)r*HKc + c0 + tx*4;
    float4 old = *(const float4*)gp;
    old.x += acc[i][0]; old.y += acc[i][1]; old.z += acc[i][2]; old.w += acc[i][3];
    *(float4*)gp = old;
  }
}

// v = relu(gout@Wv + bv); 8 rows/block, 256 threads over j-blk
__global__ void k_vgemm8(float* __restrict__ v, const float* __restrict__ vd,
                         const float* __restrict__ W, const float* __restrict__ bias, int rbase){
  int j = blockIdx.x*256 + threadIdx.x;
  int r0 = blockIdx.y*8;
  __shared__ float xr[8][Dd];
  for (int idx=threadIdx.x; idx<8*Dd; idx+=256){
    int r = idx>>7, k = idx&127;
    xr[r][k] = vd[(size_t)(rbase + r0 + r)*Dd + k];
  }
  __syncthreads();
  float acc[8];
  float bj = bias[j];
  #pragma unroll
  for (int r=0;r<8;r++) acc[r]=bj;
  for (int k=0;k<Dd;k++){
    float wk = W[(size_t)k*HKc+j];
    #pragma unroll
    for (int r=0;r<8;r++) acc[r] += xr[r][k]*wk;
  }
  #pragma unroll
  for (int r=0;r<8;r++)
    v[(size_t)(r0+r)*HKc + j] = fmaxf(acc[r],0.f);
}

__global__ void k_colsum_v(float* __restrict__ S, const float* __restrict__ X, int bbase){
  int j = blockIdx.x*blockDim.x + threadIdx.x;
  int bl = blockIdx.y;
  if (j >= HKc) return;
  const float* p = X + (size_t)bl*NPGc*HKc + j;
  float s=0.f;
  for (int t=0;t<NPGc;t++) s += p[(size_t)t*HKc];
  S[(bbase+bl)*HKc + j] = s;
}

// Fused Gv-tile (V^T V) weighted by Hsum[c]*Gq[bg,r,c] -> atomicAdd f[bg,r]
__global__ void k_gramf(float* __restrict__ f, const float* __restrict__ V,
                        const float* __restrict__ Gq_, const float* __restrict__ hm, int bbase){
  int bl = blockIdx.z, bg = bbase + bl;
  int r0 = blockIdx.y*64, c0 = blockIdx.x*64;
  const float* Vb = V + (size_t)bl*NPGc*HKc;
  __shared__ float As[16][64], Bs[16][64];
  __shared__ float wsum[64];
  int tid = threadIdx.x;
  int tx = tid & 15, ty = tid >> 4;
  int ldr = tid >> 4, ldc = (tid & 15)*4;
  if (tid < 64) wsum[tid] = hm[c0+tid] + hm[HKc + c0 + tid];
  float acc[4][4] = {};
  for (int t0=0; t0<NPGc; t0+=16){
    float4 av = make_float4(0.f,0.f,0.f,0.f), bv4 = make_float4(0.f,0.f,0.f,0.f);
    if (t0+ldr < NPGc){
      const float* row = Vb + (size_t)(t0+ldr)*HKc;
      av  = *(const float4*)(row + r0 + ldc);
      bv4 = *(const float4*)(row + c0 + ldc);
    }
    *(float4*)&As[ldr][ldc] = av;
    *(float4*)&Bs[ldr][ldc] = bv4;
    __syncthreads();
    #pragma unroll
    for (int tt=0; tt<16; tt++){
      float a[4], bb[4];
      *(float4*)a  = *(const float4*)&As[tt][ty*4];
      *(float4*)bb = *(const float4*)&Bs[tt][tx*4];
      #pragma unroll
      for (int i=0;i<4;i++)
        #pragma unroll
        for (int j=0;j<4;j++) acc[i][j] += a[i]*bb[j];
    }
    __syncthreads();
  }
  const float* gqb = Gq_ + (size_t)bg*HKc*HKc;
  float w[4];
  #pragma unroll
  for (int j=0;j<4;j++) w[j] = wsum[tx*4+j];
  #pragma unroll
  for (int i=0;i<4;i++){
    int r = r0 + ty*4 + i;
    const float4 g4 = *(const float4*)(gqb + (size_t)r*HKc + c0 + tx*4);
    float s = acc[i][0]*w[0]*g4.x + acc[i][1]*w[1]*g4.y
            + acc[i][2]*w[2]*g4.z + acc[i][3]*w[3]*g4.w;
    s += __shfl_xor(s, 1); s += __shfl_xor(s, 2);
    s += __shfl_xor(s, 4); s += __shfl_xor(s, 8);
    if (tx==0) atomicAdd(&f[bg*HKc + r], s);
  }
}

__global__ void k_pool(float* __restrict__ fp, const float* __restrict__ f,
                       const float* __restrict__ Sv, const float* __restrict__ Sq,
                       const float* __restrict__ hb){
  int idx = blockIdx.x*blockDim.x + threadIdx.x;
  if (idx >= Bc*256) return;
  int b = idx >> 8, c = idx & 255;
  float hbs = hb[0] + hb[1];
  float s = 0.f;
  #pragma unroll
  for (int r=0;r<3;r++){
    int k = c*3 + r;
    s += f[b*HKc + k] + hbs*Sv[b*HKc + k]*Sq[b*HKc + k];
  }
  fp[idx] = s;
}

// ---------------- tail ----------------
__global__ void k_bnfeat(float* __restrict__ y, const float* __restrict__ x, const float* __restrict__ g,
                         const float* __restrict__ bb, int C){
  int c = blockIdx.x; int b = threadIdx.x;
  __shared__ float buf[32];
  __shared__ float mv[2];
  float v = x[b*C + c];
  buf[b] = v;
  __syncthreads();
  if (b == 0){
    float s = 0.f;
    for (int i=0;i<32;i++) s += buf[i];
    float m = s/32.f;
    float vs = 0.f;
    for (int i=0;i<32;i++){ float d = buf[i]-m; vs += d*d; }
    mv[0] = m; mv[1] = vs/32.f;
  }
  __syncthreads();
  y[b*C + c] = (v - mv[0])*rsqrtf(mv[1]+1e-5f)*g[c] + bb[c];
}

__global__ void k_mlp(float* __restrict__ out, const float* __restrict__ in, const float* __restrict__ W,
                      const float* __restrict__ bias, int K, int Nc, int doRelu){
  int b = blockIdx.y;
  int j = blockIdx.x*blockDim.x + threadIdx.x;
  __shared__ float xr[512];
  for (int k=threadIdx.x; k<K; k+=blockDim.x) xr[k] = in[b*K+k];
  __syncthreads();
  if (j >= Nc) return;
  float s = bias[j];
  for (int k=0;k<K;k++) s += xr[k]*W[(size_t)k*Nc + j];
  if (doRelu) s = fmaxf(s, 0.f);
  out[b*Nc + j] = s;
}

__global__ void k_score(float* __restrict__ sc, const float* __restrict__ h, const float* __restrict__ w,
                        const float* __restrict__ bb){
  int b = threadIdx.x; if (b>=32) return;
  float s = bb[0];
  for (int k=0;k<Dd;k++) s += h[b*Dd+k]*w[k];
  sc[b] = s;
}

__global__ void k_out(float* __restrict__ out, const float* __restrict__ scores){
  int t = threadIdx.x;
  __shared__ float loss_s;
  if (t == 0){
    float sn1[32], sn2[32];
    for (int i=0;i<32;i++){
      float a = scores[32+i]; sn1[i] = a / fmaxf(fabsf(a), 1e-12f);
      float c = scores[64+i]; sn2[i] = c / fmaxf(fabsf(c), 1e-12f);
    }
    float acc = 0.f;
    for (int i=0;i<32;i++){
      float mx = -1e30f;
      for (int j=0;j<32;j++) mx = fmaxf(mx, sn1[i]*sn2[j]);
      float se = 0.f;
      for (int j=0;j<32;j++) se += expf(sn1[i]*sn2[j]-mx);
      acc += sn1[i]*sn2[i] - (mx + logf(se));
    }
    loss_s = -acc/32.f;
  }
  __syncthreads();
  out[t*4+0] = scores[t];
  out[t*4+1] = scores[32+t];
  out[t*4+2] = scores[64+t];
  out[t*4+3] = loss_s;
}

extern "C" void kernel_launch(void* const* d_in, const int* in_sizes, int n_in,
                              void* d_out, int out_size, void* d_ws, size_t ws_size,
                              hipStream_t stream){
  static const int exp_sizes[38] = {
    Nn*INFc, Ec, Ec, Bc*LPc, INFc*Dd,
    9*Dd*Dd, 9*Dd, 9*Dd*Dd, 9*Dd,
    26*Dd, Dd*Dd*3, Dd*Dd*6, Dd*Dd*9, 3*Dd, 3*Dd, 3*Dd,
    Dd*HKc, HKc, Dd*HKc, HKc, 2*HKc, 2, 256, 256,
    256*512, 512, 512*512, 512, 512*128, 128, 128, 1,
    512, 512, 512, 512, 128, 128 };
  if (n_in != 38){ k_sentinel<<<1,128,0,stream>>>((float*)d_out, 2000.f + n_in); return; }
  for (int i=0;i<38;i++){
    if (in_sizes[i] != exp_sizes[i]){
      k_sentinel<<<1,128,0,stream>>>((float*)d_out, 1000.f + i); return;
    }
  }

  const float* node_h=(const float*)d_in[0];
  const int*  esrc  =(const int*)d_in[1];
  const int*  edst  =(const int*)d_in[2];
  const int*  vp    =(const int*)d_in[3];
  const float* W_init=(const float*)d_in[4];
  const float* gcn_W =(const float*)d_in[5];
  const float* gcn_b =(const float*)d_in[6];
  const float* gcn_Wr=(const float*)d_in[7];
  const float* gcn_br=(const float*)d_in[8];
  const float* emb   =(const float*)d_in[9];
  const float* c1w=(const float*)d_in[10];
  const float* c2w=(const float*)d_in[11];
  const float* c3w=(const float*)d_in[12];
  const float* cbv=(const float*)d_in[13];
  const float* bng=(const float*)d_in[14];
  const float* bnb=(const float*)d_in[15];
  const float* Wv =(const float*)d_in[16];
  const float* bvv=(const float*)d_in[17];
  const float* Wq =(const float*)d_in[18];
  const float* bq =(const float*)d_in[19];
  const float* hmat =(const float*)d_in[20];
  const float* hbias=(const float*)d_in[21];
  const float* bang =(const float*)d_in[22];
  const float* banb =(const float*)d_in[23];
  const float* mw1=(const float*)d_in[24]; const float* mb1=(const float*)d_in[25];
  const float* mw2=(const float*)d_in[26]; const float* mb2=(const float*)d_in[27];
  const float* mw3=(const float*)d_in[28]; const float* mb3=(const float*)d_in[29];
  const float* mw4=(const float*)d_in[30]; const float* mb4=(const float*)d_in[31];
  const float* g1=(const float*)d_in[32]; const float* bb1=(const float*)d_in[33];
  const float* g2=(const float*)d_in[34]; const float* bb2=(const float*)d_in[35];
  const float* g3=(const float*)d_in[36]; const float* bb3=(const float*)d_in[37];

  float* ws = (float*)d_ws;
  size_t off = 0;
  auto alloc = [&](size_t n){ float* p = ws + off; off += n; return p; };

  const size_t NDsz = (size_t)Nn*Dd;              // 1,187,840
  const size_t CNNB = (size_t)Bc*Dd*LPc;          // 3,686,400
  const size_t ADJ  = (size_t)Bc*NPGc*NPGc;       // 2,691,200
  size_t ARENA = 4*NDsz + ADJ;                    // 7,442,560
  if (ARENA < 2*CNNB) ARENA = 2*CNNB;

  // smalls
  float* Sq  = alloc((size_t)Bc*HKc);
  float* Sv  = alloc((size_t)Bc*HKc);
  float* fbuf= alloc((size_t)Bc*HKc);
  float* fpool=alloc((size_t)Bc*256);
  float* hh1 = alloc((size_t)Bc*512);
  float* hh2 = alloc((size_t)Bc*512);
  float* hh3 = alloc((size_t)Bc*128);
  float* sc  = alloc(96);
  float* bnm = alloc(128);
  float* bnr = alloc(128);
  // persistent fp32 Gq
  float* Gq  = alloc((size_t)Bc*HKc*HKc);         // 18,874,368
  // phase-overlapped arena
  float* arena = alloc(ARENA);
  // total ≈ 26.44M floats ≈ 105.8 MiB

  // phase views
  float* cnnA = arena;                 // CNN out (885-wide) / later A0
  float* cnnB = arena + CNNB;
  float* qc   = arena + CNNB;          // 32*128*768 = 3,145,728
  float* A0 = arena;
  float* A1 = arena + NDsz;
  float* A2t= arena + 2*NDsz;
  float* A3 = arena + 3*NDsz;
  float* vbuf = arena + NDsz;          // 16*290*768 ends at 4*NDsz
  float* Adj  = arena + 4*NDsz;        // built AFTER q-phase

  // ---- ProteinCNN (ping-pong; final output in cnnA) ----
  k_embed<<<dim3((LPc+127)/128, Dd, Bc),128,0,stream>>>(cnnB, vp, emb);
  k_conv_t<3><<<dim3((898+CT-1)/CT,Bc),256,Dd*(CT+2)*sizeof(float),stream>>>(cnnA, cnnB, c1w, cbv, 900, 898, 0);
  k_bnc_stats<<<Dd,256,0,stream>>>(bnm,bnr,cnnA,898);
  { size_t t0=(size_t)Bc*Dd*898;
    k_bnc_apply<<<(unsigned)((t0+255)/256),256,0,stream>>>(cnnA,bnm,bnr,bng,bnb,898,0); }
  k_conv_t<6><<<dim3((893+CT-1)/CT,Bc),256,Dd*(CT+5)*sizeof(float),stream>>>(cnnB, cnnA, c2w, cbv, 898, 893, 128);
  k_bnc_stats<<<Dd,256,0,stream>>>(bnm,bnr,cnnB,893);
  { size_t t1=(size_t)Bc*Dd*893;
    k_bnc_apply<<<(unsigned)((t1+255)/256),256,0,stream>>>(cnnB,bnm,bnr,bng,bnb,893,128); }
  k_conv_t<9><<<dim3((885+CT-1)/CT,Bc),256,Dd*(CT+8)*sizeof(float),stream>>>(cnnA, cnnB, c3w, cbv, 893, 885, 256);
  k_bnc_stats<<<Dd,256,0,stream>>>(bnm,bnr,cnnA,885);
  { size_t t2=(size_t)Bc*Dd*885;
    k_bnc_apply<<<(unsigned)((t2+255)/256),256,0,stream>>>(cnnA,bnm,bnr,bng,bnb,885,256); }

  // ---- q branch: chunked fp32 Gq/Sq accumulation ----
  hipMemsetAsync(Gq, 0, (size_t)Bc*HKc*HKc*sizeof(float), stream);
  hipMemsetAsync(Sq, 0, (size_t)Bc*HKc*sizeof(float), stream);
  for (int t0c = 0; t0c < LQ; t0c += CHT){
    int Tc = LQ - t0c; if (Tc > CHT) Tc = CHT;
    k_qgemm_tile<<<dim3(12,(Tc+63)/64,Bc),256,0,stream>>>(qc, cnnA, Wq, bq, t0c, Tc);
    k_colsum_acc<<<dim3(3,Bc),256,0,stream>>>(Sq, qc, Tc);
    k_gram_acc<<<dim3(12,12,Bc),256,0,stream>>>(Gq, qc, Tc);
  }

  // ---- dense adjacency (edges fixed; built once, after q-phase frees the space) ----
  hipMemsetAsync(Adj, 0, ADJ*sizeof(float), stream);
  k_build_adj<<<(Ec+255)/256,256,0,stream>>>(Adj, esrc, edst);

  // ---- three GCN branches + Gram-fused BAN + MLPs ----
  for (int g=0; g<3; g++){
    k_h0<<<Nn,Dd,0,stream>>>(A1, node_h, W_init);
    // l=0: A1 -> A3
    k_aggmm<<<dim3(37,Bc),128,0,stream>>>(A2t, Adj, A1);
    { int wo=g*3+0;
      k_gcn8<<<Nn/8,Dd,0,stream>>>(A3, A2t, A1, gcn_W+(size_t)wo*Dd*Dd, gcn_b+(size_t)wo*Dd,
                                   gcn_Wr+(size_t)wo*Dd*Dd, gcn_br+(size_t)wo*Dd); }
    // l=1: A3 -> A1
    k_aggmm<<<dim3(37,Bc),128,0,stream>>>(A2t, Adj, A3);
    { int wo=g*3+1;
      k_gcn8<<<Nn/8,Dd,0,stream>>>(A1, A2t, A3, gcn_W+(size_t)wo*Dd*Dd, gcn_b+(size_t)wo*Dd,
                                   gcn_Wr+(size_t)wo*Dd*Dd, gcn_br+(size_t)wo*Dd); }
    // l=2: A1 -> A0
    k_aggmm<<<dim3(37,Bc),128,0,stream>>>(A2t, Adj, A1);
    { int wo=g*3+2;
      k_gcn8<<<Nn/8,Dd,0,stream>>>(A0, A2t, A1, gcn_W+(size_t)wo*Dd*Dd, gcn_b+(size_t)wo*Dd,
                                   gcn_Wr+(size_t)wo*Dd*Dd, gcn_br+(size_t)wo*Dd); }

    // BAN view in two half-batches of 16 graphs
    hipMemsetAsync(fbuf, 0, (size_t)Bc*HKc*sizeof(float), stream);
    for (int p=0; p<2; p++){
      int bbase = p*16;
      k_vgemm8<<<dim3(3,(16*NPGc)/8),256,0,stream>>>(vbuf, A0, Wv, bvv, bbase*NPGc);
      k_colsum_v<<<dim3(3,16),256,0,stream>>>(Sv, vbuf, bbase);
      k_gramf<<<dim3(12,12,16),256,0,stream>>>(fbuf, vbuf, Gq, hmat, bbase);
    }
    k_pool<<<(Bc*256+255)/256,256,0,stream>>>(fpool, fbuf, Sv, Sq, hbias);
    k_bnfeat<<<256,32,0,stream>>>(fpool, fpool, bang, banb, 256);
    k_mlp<<<dim3(2,Bc),256,0,stream>>>(hh1, fpool, mw1, mb1, 256, 512, 1);
    k_bnfeat<<<512,32,0,stream>>>(hh1,hh1,g1,bb1,512);
    k_mlp<<<dim3(2,Bc),256,0,stream>>>(hh2, hh1, mw2, mb2, 512, 512, 1);
    k_bnfeat<<<512,32,0,stream>>>(hh2,hh2,g2,bb2,512);
    k_mlp<<<dim3(1,Bc),256,0,stream>>>(hh3, hh2, mw3, mb3, 512, 128, 1);
    k_bnfeat<<<128,32,0,stream>>>(hh3,hh3,g3,bb3,128);
    k_score<<<1,32,0,stream>>>(sc + 32*g, hh3, mw4, mb4);
  }

  k_out<<<1,32,0,stream>>>((float*)d_out, sc);
}

// Round 11
// 2758.410 us; speedup vs baseline: 29.3842x; 1.2202x over previous
//
#include <hip/hip_runtime.h>
#include <hip/hip_bf16.h>

#define Bc 32
#define NPGc 290
#define Nn 9280
#define Ec 74240
#define LPc 900
#define INFc 75
#define Dd 128
#define HKc 768
#define LQ 885
#define CHT 128   // q-chunk timesteps
// padded strides (multiples of 4 -> aligned float4 rows)
#define S1 904    // conv1 out (898)
#define S2 896    // conv2 out (893)
#define S3 888    // conv3 out (885)

__global__ void k_sentinel(float* out, float val){
  int t = threadIdx.x;
  if (t < 128) out[t] = val;
}

// ---------------- GCN ----------------
__global__ void k_h0(float* __restrict__ h0, const float* __restrict__ nh, const float* __restrict__ Wi){
  int n = blockIdx.x, j = threadIdx.x;
  __shared__ float arow[INFc];
  if (j < INFc) arow[j] = nh[(size_t)n*INFc + j];
  __syncthreads();
  float s = 0.f;
  #pragma unroll 5
  for (int k=0;k<INFc;k++) s += arow[k]*Wi[(size_t)k*Dd + j];
  h0[(size_t)n*Dd + j] = s;
}

__global__ void k_build_adj(float* __restrict__ A, const int* __restrict__ src, const int* __restrict__ dst){
  int e = blockIdx.x*blockDim.x + threadIdx.x;
  if (e >= Ec) return;
  int s = src[e], d = dst[e];
  int b = d / NPGc;
  int dl = d - b*NPGc, sl = s - b*NPGc;
  atomicAdd(&A[((size_t)b*NPGc + dl)*NPGc + sl], 1.f);
}

// fused: agg = A·h (8 rows) then out = relu(agg@W+b)+relu(h@Wr+br)
__global__ void k_gcn_fused(float* __restrict__ out, const float* __restrict__ A, const float* __restrict__ h,
                            const float* __restrict__ W, const float* __restrict__ bvec,
                            const float* __restrict__ Wr, const float* __restrict__ br){
  int b = blockIdx.y;
  int i0 = blockIdx.x*8;
  int j = threadIdx.x;  // 128
  __shared__ float arow[8][NPGc];
  __shared__ float ar[8][Dd], hr[8][Dd];
  for (int idx=j; idx<8*NPGc; idx+=128){
    int r=idx/NPGc, c=idx-r*NPGc;
    arow[r][c] = (i0+r<NPGc) ? A[((size_t)b*NPGc+i0+r)*NPGc+c] : 0.f;
  }
  for (int idx=j; idx<8*Dd; idx+=128){
    int r=idx>>7, k=idx&127;
    hr[r][k] = (i0+r<NPGc) ? h[((size_t)b*NPGc+i0+r)*Dd+k] : 0.f;
  }
  __syncthreads();
  float acc[8]={};
  const float* hb = h + (size_t)b*NPGc*Dd + j;
  for (int c=0;c<NPGc;c++){
    float hv = hb[(size_t)c*Dd];
    #pragma unroll
    for (int r=0;r<8;r++) acc[r] += arow[r][c]*hv;
  }
  #pragma unroll
  for (int r=0;r<8;r++) ar[r][j] = acc[r];
  __syncthreads();
  float s1[8], s2[8];
  float bj = bvec[j], brj = br[j];
  #pragma unroll
  for (int r=0;r<8;r++){ s1[r]=bj; s2[r]=brj; }
  for (int k=0;k<Dd;k++){
    float wk = W[(size_t)k*Dd+j], wrk = Wr[(size_t)k*Dd+j];
    #pragma unroll
    for (int r=0;r<8;r++){ s1[r] += ar[r][k]*wk; s2[r] += hr[r][k]*wrk; }
  }
  int nr = NPGc - i0; if (nr > 8) nr = 8;
  for (int r=0;r<nr;r++)
    out[((size_t)b*NPGc+i0+r)*Dd + j] = fmaxf(s1[r],0.f) + fmaxf(s2[r],0.f);
}

// ---------------- ProteinCNN ----------------
__global__ void k_embed(float* __restrict__ x, const int* __restrict__ vp, const float* __restrict__ emb){
  int t = blockIdx.x*blockDim.x + threadIdx.x;
  int d = blockIdx.y, b = blockIdx.z;
  if (t >= LPc) return;
  int tok = vp[b*LPc + t];
  x[((size_t)b*Dd + d)*LPc + t] = emb[(size_t)tok*Dd + d];
}

// transpose conv weights: wT[(i*KW+k)*128 + o] = w[(o*128+i)*KW + k]
__global__ void k_wT(float* __restrict__ wT, const float* __restrict__ w, int KW){
  int idx = blockIdx.x*256 + threadIdx.x;
  int tot = Dd*Dd*KW;
  if (idx >= tot) return;
  int o = idx & 127; int rest = idx >> 7;
  wT[(size_t)rest*Dd + o] = w[((size_t)o*Dd + rest/KW)*KW + (rest % KW)];
}

// conv as tiled GEMM: M=o(128), N=t(Lout), K=128*KW (implicit im2col)
template<int KW>
__global__ void k_convg(float* __restrict__ y, const float* __restrict__ x, const float* __restrict__ wT,
                        const float* __restrict__ cb, int Lin, int Lout, int XS, int YS, int cbo){
  int b = blockIdx.z;
  int o0 = blockIdx.y*64;
  int t0 = blockIdx.x*64;
  __shared__ float As[16][64], Bs[16][64];
  int tid=threadIdx.x, tx=tid&15, ty=tid>>4;
  int ldr=tid>>4, ldc=(tid&15)*4;
  float acc[4][4]={};
  const int KT = Dd*KW;
  for (int k0=0; k0<KT; k0+=16){
    *(float4*)&As[ldr][ldc] = *(const float4*)(wT + (size_t)(k0+ldr)*Dd + o0 + ldc);
    int kk = k0+ldr; int i = kk/KW, k = kk - i*KW;
    const float* xr = x + ((size_t)b*Dd + i)*XS + t0 + k + ldc;
    int tb = t0 + k + ldc;
    float b0 = (tb+0 < Lin)? xr[0]:0.f;
    float b1 = (tb+1 < Lin)? xr[1]:0.f;
    float b2 = (tb+2 < Lin)? xr[2]:0.f;
    float b3 = (tb+3 < Lin)? xr[3]:0.f;
    Bs[ldr][ldc+0]=b0; Bs[ldr][ldc+1]=b1; Bs[ldr][ldc+2]=b2; Bs[ldr][ldc+3]=b3;
    __syncthreads();
    #pragma unroll
    for (int kk2=0;kk2<16;kk2++){
      float a[4], bb[4];
      *(float4*)a  = *(const float4*)&As[kk2][ty*4];
      *(float4*)bb = *(const float4*)&Bs[kk2][tx*4];
      #pragma unroll
      for (int i2=0;i2<4;i2++)
        #pragma unroll
        for (int j2=0;j2<4;j2++) acc[i2][j2] += a[i2]*bb[j2];
    }
    __syncthreads();
  }
  int t = t0 + tx*4;
  #pragma unroll
  for (int i2=0;i2<4;i2++){
    int o = o0+ty*4+i2;
    float bias = cb[cbo+o];
    float* yp = y + ((size_t)b*Dd+o)*YS + t;
    if (t+3 < Lout){
      float4 v;
      v.x = fmaxf(acc[i2][0]+bias,0.f); v.y = fmaxf(acc[i2][1]+bias,0.f);
      v.z = fmaxf(acc[i2][2]+bias,0.f); v.w = fmaxf(acc[i2][3]+bias,0.f);
      *(float4*)yp = v;
    } else {
      for (int j2=0;j2<4;j2++) if (t+j2 < Lout) yp[j2] = fmaxf(acc[i2][j2]+bias,0.f);
    }
  }
}

__global__ void k_bnc_stats(float* __restrict__ mean, float* __restrict__ rstd,
                            const float* __restrict__ y, int Lout, int YS){
  int c = blockIdx.x;
  float s=0.f, ss=0.f;
  int cnt = Bc*Lout;
  for (int i = threadIdx.x; i < cnt; i += blockDim.x){
    int b = i / Lout, t = i - b*Lout;
    float v = y[((size_t)b*Dd+c)*YS + t];
    s += v; ss += v*v;
  }
  __shared__ float rs[256], rss[256];
  rs[threadIdx.x]=s; rss[threadIdx.x]=ss; __syncthreads();
  for (int st=128; st>0; st>>=1){
    if (threadIdx.x<st){ rs[threadIdx.x]+=rs[threadIdx.x+st]; rss[threadIdx.x]+=rss[threadIdx.x+st]; }
    __syncthreads();
  }
  if (threadIdx.x==0){
    float m = rs[0]/cnt; float v = rss[0]/cnt - m*m; if (v<0.f) v=0.f;
    mean[c]=m; rstd[c]=rsqrtf(v+1e-5f);
  }
}

__global__ void k_bnc_apply(float* __restrict__ y, const float* __restrict__ mean, const float* __restrict__ rstd,
                            const float* __restrict__ g, const float* __restrict__ bb, int Lout, int YS, int go){
  size_t idx = (size_t)blockIdx.x*blockDim.x + threadIdx.x;
  size_t tot = (size_t)Bc*Dd*Lout;
  if (idx >= tot) return;
  int t = (int)(idx % Lout);
  int r = (int)(idx / Lout);
  int c = r & (Dd-1);
  size_t a = (size_t)r*YS + t;
  y[a] = (y[a]-mean[c])*rstd[c]*g[go+c] + bb[go+c];
}

// ---------------- BAN via Gram factorization (upper-triangle only) ----------------
// qc[b,m,j] = relu( X^T W + bias ); X stride S3
__global__ void k_qgemm_tile(float* __restrict__ qc, const float* __restrict__ x,
                             const float* __restrict__ W, const float* __restrict__ bias,
                             int t0c, int Tc){
  int b = blockIdx.z;
  int m0 = blockIdx.y*64;
  int n0 = blockIdx.x*64;
  __shared__ float As[16][64], Bs[16][64];
  int tid = threadIdx.x;
  int tx = tid & 15, ty = tid >> 4;
  int ldr = tid >> 4, ldc = (tid & 15)*4;
  float acc[4][4] = {};
  for (int k0 = 0; k0 < Dd; k0 += 16){
    const float* xrow = x + ((size_t)b*Dd + k0 + ldr)*S3 + t0c + m0 + ldc;
    int mb = m0 + ldc;
    float a0 = (mb+0 < Tc) ? xrow[0] : 0.f;
    float a1 = (mb+1 < Tc) ? xrow[1] : 0.f;
    float a2 = (mb+2 < Tc) ? xrow[2] : 0.f;
    float a3 = (mb+3 < Tc) ? xrow[3] : 0.f;
    As[ldr][ldc+0]=a0; As[ldr][ldc+1]=a1; As[ldr][ldc+2]=a2; As[ldr][ldc+3]=a3;
    *(float4*)&Bs[ldr][ldc] = *(const float4*)(W + (size_t)(k0+ldr)*HKc + n0 + ldc);
    __syncthreads();
    #pragma unroll
    for (int kk=0; kk<16; kk++){
      float a[4], bb[4];
      *(float4*)a  = *(const float4*)&As[kk][ty*4];
      *(float4*)bb = *(const float4*)&Bs[kk][tx*4];
      #pragma unroll
      for (int i=0;i<4;i++)
        #pragma unroll
        for (int j=0;j<4;j++) acc[i][j] += a[i]*bb[j];
    }
    __syncthreads();
  }
  #pragma unroll
  for (int i=0;i<4;i++){
    int m = m0 + ty*4 + i;
    if (m >= Tc) continue;
    int n = n0 + tx*4;
    float4 o;
    o.x = fmaxf(acc[i][0] + bias[n+0], 0.f);
    o.y = fmaxf(acc[i][1] + bias[n+1], 0.f);
    o.z = fmaxf(acc[i][2] + bias[n+2], 0.f);
    o.w = fmaxf(acc[i][3] + bias[n+3], 0.f);
    *(float4*)(qc + ((size_t)b*CHT + m)*HKc + n) = o;
  }
}

__global__ void k_colsum_acc(float* __restrict__ S, const float* __restrict__ X, int Tc){
  int j = blockIdx.x*blockDim.x + threadIdx.x;
  int b = blockIdx.y;
  if (j >= HKc) return;
  const float* p = X + (size_t)b*CHT*HKc + j;
  float s=0.f;
  for (int t=0;t<Tc;t++) s += p[(size_t)t*HKc];
  S[b*HKc + j] += s;
}

// Gq upper-triangle tiles only: blockIdx.x in [0,78) -> (ti<=tj)
__global__ void k_gram_acc_sym(float* __restrict__ G, const float* __restrict__ X, int Tc){
  int b = blockIdx.y;
  int tl = blockIdx.x; int ti = 0;
  while (tl >= 12-ti){ tl -= 12-ti; ti++; }
  int tj = ti + tl;
  int r0 = ti*64, c0 = tj*64;
  const float* Xb = X + (size_t)b*CHT*HKc;
  float* Gb = G + (size_t)b*HKc*HKc;
  __shared__ float As[16][64], Bs[16][64];
  int tid = threadIdx.x;
  int tx = tid & 15, ty = tid >> 4;
  int ldr = tid >> 4, ldc = (tid & 15)*4;
  float acc[4][4] = {};
  for (int t0=0; t0<Tc; t0+=16){
    float4 av = make_float4(0.f,0.f,0.f,0.f), bv4 = make_float4(0.f,0.f,0.f,0.f);
    if (t0+ldr < Tc){
      const float* row = Xb + (size_t)(t0+ldr)*HKc;
      av  = *(const float4*)(row + r0 + ldc);
      bv4 = *(const float4*)(row + c0 + ldc);
    }
    *(float4*)&As[ldr][ldc] = av;
    *(float4*)&Bs[ldr][ldc] = bv4;
    __syncthreads();
    #pragma unroll
    for (int tt=0; tt<16; tt++){
      float a[4], bb[4];
      *(float4*)a  = *(const float4*)&As[tt][ty*4];
      *(float4*)bb = *(const float4*)&Bs[tt][tx*4];
      #pragma unroll
      for (int i=0;i<4;i++)
        #pragma unroll
        for (int j=0;j<4;j++) acc[i][j] += a[i]*bb[j];
    }
    __syncthreads();
  }
  for (int i=0;i<4;i++){
    int r = r0 + ty*4 + i;
    float* gp = Gb + (size_t)r*HKc + c0 + tx*4;
    float4 old = *(const float4*)gp;
    old.x += acc[i][0]; old.y += acc[i][1]; old.z += acc[i][2]; old.w += acc[i][3];
    *(float4*)gp = old;
  }
}

__global__ void k_vgemm8(float* __restrict__ v, const float* __restrict__ vd,
                         const float* __restrict__ W, const float* __restrict__ bias, int rbase){
  int j = blockIdx.x*256 + threadIdx.x;
  int r0 = blockIdx.y*8;
  __shared__ float xr[8][Dd];
  for (int idx=threadIdx.x; idx<8*Dd; idx+=256){
    int r = idx>>7, k = idx&127;
    xr[r][k] = vd[(size_t)(rbase + r0 + r)*Dd + k];
  }
  __syncthreads();
  float acc[8];
  float bj = bias[j];
  #pragma unroll
  for (int r=0;r<8;r++) acc[r]=bj;
  for (int k=0;k<Dd;k++){
    float wk = W[(size_t)k*HKc+j];
    #pragma unroll
    for (int r=0;r<8;r++) acc[r] += xr[r][k]*wk;
  }
  #pragma unroll
  for (int r=0;r<8;r++)
    v[(size_t)(r0+r)*HKc + j] = fmaxf(acc[r],0.f);
}

__global__ void k_colsum_v(float* __restrict__ S, const float* __restrict__ X, int bbase){
  int j = blockIdx.x*blockDim.x + threadIdx.x;
  int bl = blockIdx.y;
  if (j >= HKc) return;
  const float* p = X + (size_t)bl*NPGc*HKc + j;
  float s=0.f;
  for (int t=0;t<NPGc;t++) s += p[(size_t)t*HKc];
  S[(bbase+bl)*HKc + j] = s;
}

// gramf over upper-triangle tiles; off-diag tiles contribute to BOTH row ranges
__global__ void k_gramf_sym(float* __restrict__ f, const float* __restrict__ V,
                            const float* __restrict__ Gq_, const float* __restrict__ hm, int bbase){
  int bl = blockIdx.z, bg = bbase + bl;
  int tl = blockIdx.x; int ti = 0;
  while (tl >= 12-ti){ tl -= 12-ti; ti++; }
  int tj = ti + tl;
  int r0 = ti*64, c0 = tj*64;
  int offdiag = (ti != tj);
  const float* Vb = V + (size_t)bl*NPGc*HKc;
  __shared__ float As[16][64], Bs[16][64];
  __shared__ float wc[64], wr[64];
  int tid = threadIdx.x;
  int tx = tid & 15, ty = tid >> 4;
  int ldr = tid >> 4, ldc = (tid & 15)*4;
  if (tid < 64) wc[tid] = hm[c0+tid] + hm[HKc + c0 + tid];
  else if (tid < 128) wr[tid-64] = hm[r0+tid-64] + hm[HKc + r0 + tid-64];
  float acc[4][4] = {};
  for (int t0=0; t0<NPGc; t0+=16){
    float4 av = make_float4(0.f,0.f,0.f,0.f), bv4 = make_float4(0.f,0.f,0.f,0.f);
    if (t0+ldr < NPGc){
      const float* row = Vb + (size_t)(t0+ldr)*HKc;
      av  = *(const float4*)(row + r0 + ldc);
      bv4 = *(const float4*)(row + c0 + ldc);
    }
    *(float4*)&As[ldr][ldc] = av;
    *(float4*)&Bs[ldr][ldc] = bv4;
    __syncthreads();
    #pragma unroll
    for (int tt=0; tt<16; tt++){
      float a[4], bb[4];
      *(float4*)a  = *(const float4*)&As[tt][ty*4];
      *(float4*)bb = *(const float4*)&Bs[tt][tx*4];
      #pragma unroll
      for (int i=0;i<4;i++)
        #pragma unroll
        for (int j=0;j<4;j++) acc[i][j] += a[i]*bb[j];
    }
    __syncthreads();
  }
  const float* gqb = Gq_ + (size_t)bg*HKc*HKc;
  float w0 = wc[tx*4+0], w1 = wc[tx*4+1], w2 = wc[tx*4+2], w3 = wc[tx*4+3];
  float colp[4] = {0.f,0.f,0.f,0.f};
  #pragma unroll
  for (int i=0;i<4;i++){
    int r = r0 + ty*4 + i;
    const float4 g4 = *(const float4*)(gqb + (size_t)r*HKc + c0 + tx*4);
    float s = acc[i][0]*w0*g4.x + acc[i][1]*w1*g4.y
            + acc[i][2]*w2*g4.z + acc[i][3]*w3*g4.w;
    s += __shfl_xor(s, 1); s += __shfl_xor(s, 2);
    s += __shfl_xor(s, 4); s += __shfl_xor(s, 8);
    if (tx==0) atomicAdd(&f[bg*HKc + r], s);
    if (offdiag){
      float wri = wr[ty*4+i];
      colp[0] += acc[i][0]*wri*g4.x;
      colp[1] += acc[i][1]*wri*g4.y;
      colp[2] += acc[i][2]*wri*g4.z;
      colp[3] += acc[i][3]*wri*g4.w;
    }
  }
  if (offdiag){
    #pragma unroll
    for (int j=0;j<4;j++){
      colp[j] += __shfl_xor(colp[j], 16);
      colp[j] += __shfl_xor(colp[j], 32);
    }
    if ((tid & 48) == 0){
      #pragma unroll
      for (int j=0;j<4;j++)
        atomicAdd(&f[bg*HKc + c0 + tx*4 + j], colp[j]);
    }
  }
}

__global__ void k_pool(float* __restrict__ fp, const float* __restrict__ f,
                       const float* __restrict__ Sv, const float* __restrict__ Sq,
                       const float* __restrict__ hb){
  int idx = blockIdx.x*blockDim.x + threadIdx.x;
  if (idx >= Bc*256) return;
  int b = idx >> 8, c = idx & 255;
  float hbs = hb[0] + hb[1];
  float s = 0.f;
  #pragma unroll
  for (int r=0;r<3;r++){
    int k = c*3 + r;
    s += f[b*HKc + k] + hbs*Sv[b*HKc + k]*Sq[b*HKc + k];
  }
  fp[idx] = s;
}

// ---------------- tail ----------------
__global__ void k_bnfeat(float* __restrict__ y, const float* __restrict__ x, const float* __restrict__ g,
                         const float* __restrict__ bb, int C){
  int c = blockIdx.x; int b = threadIdx.x;
  __shared__ float buf[32];
  __shared__ float mv[2];
  float v = x[b*C + c];
  buf[b] = v;
  __syncthreads();
  if (b == 0){
    float s = 0.f;
    for (int i=0;i<32;i++) s += buf[i];
    float m = s/32.f;
    float vs = 0.f;
    for (int i=0;i<32;i++){ float d = buf[i]-m; vs += d*d; }
    mv[0] = m; mv[1] = vs/32.f;
  }
  __syncthreads();
  y[b*C + c] = (v - mv[0])*rsqrtf(mv[1]+1e-5f)*g[c] + bb[c];
}

__global__ void k_mlp(float* __restrict__ out, const float* __restrict__ in, const float* __restrict__ W,
                      const float* __restrict__ bias, int K, int Nc, int doRelu){
  int b = blockIdx.y;
  int j = blockIdx.x*blockDim.x + threadIdx.x;
  __shared__ float xr[512];
  for (int k=threadIdx.x; k<K; k+=blockDim.x) xr[k] = in[b*K+k];
  __syncthreads();
  if (j >= Nc) return;
  float s = bias[j];
  for (int k=0;k<K;k++) s += xr[k]*W[(size_t)k*Nc + j];
  if (doRelu) s = fmaxf(s, 0.f);
  out[b*Nc + j] = s;
}

__global__ void k_score(float* __restrict__ sc, const float* __restrict__ h, const float* __restrict__ w,
                        const float* __restrict__ bb){
  int b = threadIdx.x; if (b>=32) return;
  float s = bb[0];
  for (int k=0;k<Dd;k++) s += h[b*Dd+k]*w[k];
  sc[b] = s;
}

__global__ void k_out(float* __restrict__ out, const float* __restrict__ scores){
  int t = threadIdx.x;
  __shared__ float loss_s;
  if (t == 0){
    float sn1[32], sn2[32];
    for (int i=0;i<32;i++){
      float a = scores[32+i]; sn1[i] = a / fmaxf(fabsf(a), 1e-12f);
      float c = scores[64+i]; sn2[i] = c / fmaxf(fabsf(c), 1e-12f);
    }
    float acc = 0.f;
    for (int i=0;i<32;i++){
      float mx = -1e30f;
      for (int j=0;j<32;j++) mx = fmaxf(mx, sn1[i]*sn2[j]);
      float se = 0.f;
      for (int j=0;j<32;j++) se += expf(sn1[i]*sn2[j]-mx);
      acc += sn1[i]*sn2[i] - (mx + logf(se));
    }
    loss_s = -acc/32.f;
  }
  __syncthreads();
  out[t*4+0] = scores[t];
  out[t*4+1] = scores[32+t];
  out[t*4+2] = scores[64+t];
  out[t*4+3] = loss_s;
}

extern "C" void kernel_launch(void* const* d_in, const int* in_sizes, int n_in,
                              void* d_out, int out_size, void* d_ws, size_t ws_size,
                              hipStream_t stream){
  static const int exp_sizes[38] = {
    Nn*INFc, Ec, Ec, Bc*LPc, INFc*Dd,
    9*Dd*Dd, 9*Dd, 9*Dd*Dd, 9*Dd,
    26*Dd, Dd*Dd*3, Dd*Dd*6, Dd*Dd*9, 3*Dd, 3*Dd, 3*Dd,
    Dd*HKc, HKc, Dd*HKc, HKc, 2*HKc, 2, 256, 256,
    256*512, 512, 512*512, 512, 512*128, 128, 128, 1,
    512, 512, 512, 512, 128, 128 };
  if (n_in != 38){ k_sentinel<<<1,128,0,stream>>>((float*)d_out, 2000.f + n_in); return; }
  for (int i=0;i<38;i++){
    if (in_sizes[i] != exp_sizes[i]){
      k_sentinel<<<1,128,0,stream>>>((float*)d_out, 1000.f + i); return;
    }
  }

  const float* node_h=(const float*)d_in[0];
  const int*  esrc  =(const int*)d_in[1];
  const int*  edst  =(const int*)d_in[2];
  const int*  vp    =(const int*)d_in[3];
  const float* W_init=(const float*)d_in[4];
  const float* gcn_W =(const float*)d_in[5];
  const float* gcn_b =(const float*)d_in[6];
  const float* gcn_Wr=(const float*)d_in[7];
  const float* gcn_br=(const float*)d_in[8];
  const float* emb   =(const float*)d_in[9];
  const float* c1w=(const float*)d_in[10];
  const float* c2w=(const float*)d_in[11];
  const float* c3w=(const float*)d_in[12];
  const float* cbv=(const float*)d_in[13];
  const float* bng=(const float*)d_in[14];
  const float* bnb=(const float*)d_in[15];
  const float* Wv =(const float*)d_in[16];
  const float* bvv=(const float*)d_in[17];
  const float* Wq =(const float*)d_in[18];
  const float* bq =(const float*)d_in[19];
  const float* hmat =(const float*)d_in[20];
  const float* hbias=(const float*)d_in[21];
  const float* bang =(const float*)d_in[22];
  const float* banb =(const float*)d_in[23];
  const float* mw1=(const float*)d_in[24]; const float* mb1=(const float*)d_in[25];
  const float* mw2=(const float*)d_in[26]; const float* mb2=(const float*)d_in[27];
  const float* mw3=(const float*)d_in[28]; const float* mb3=(const float*)d_in[29];
  const float* mw4=(const float*)d_in[30]; const float* mb4=(const float*)d_in[31];
  const float* g1=(const float*)d_in[32]; const float* bb1=(const float*)d_in[33];
  const float* g2=(const float*)d_in[34]; const float* bb2=(const float*)d_in[35];
  const float* g3=(const float*)d_in[36]; const float* bb3=(const float*)d_in[37];

  float* ws = (float*)d_ws;
  size_t off = 0;
  auto alloc = [&](size_t n){ float* p = ws + off; off += n; return p; };

  const size_t NDsz = (size_t)Nn*Dd;              // 1,187,840
  const size_t CNNBP = (size_t)Bc*Dd*S1;          // 3,702,784 (padded buffer)
  const size_t ADJ  = (size_t)Bc*NPGc*NPGc;       // 2,691,200
  size_t ARENA = 4*NDsz + ADJ;                    // 7,442,560
  if (ARENA < 2*CNNBP) ARENA = 2*CNNBP;           // 7,405,568 < above

  // smalls
  float* Sq  = alloc((size_t)Bc*HKc);
  float* Sv  = alloc((size_t)Bc*HKc);
  float* fbuf= alloc((size_t)Bc*HKc);
  float* fpool=alloc((size_t)Bc*256);
  float* hh1 = alloc((size_t)Bc*512);
  float* hh2 = alloc((size_t)Bc*512);
  float* hh3 = alloc((size_t)Bc*128);
  float* sc  = alloc(96);
  float* bnm = alloc(128);
  float* bnr = alloc(128);
  float* wT1 = alloc((size_t)Dd*Dd*3);
  float* wT2 = alloc((size_t)Dd*Dd*6);
  float* wT3 = alloc((size_t)Dd*Dd*9);
  // persistent fp32 Gq (upper triangle valid)
  float* Gq  = alloc((size_t)Bc*HKc*HKc);         // 18,874,368
  // phase-overlapped arena
  float* arena = alloc(ARENA);
  // total ≈ 26.7M floats ≈ 107 MiB

  // phase views
  float* cnnA = arena;                 // padded stride buffers
  float* cnnB = arena + CNNBP;
  float* qc   = arena + CNNBP;         // 32*128*768 = 3,145,728
  float* A0 = arena;
  float* A1 = arena + NDsz;
  float* A2t= arena + 2*NDsz;
  float* A3 = arena + 3*NDsz;
  float* vbuf = arena + NDsz;
  float* Adj  = arena + 4*NDsz;

  // ---- conv weight transposes ----
  k_wT<<<(Dd*Dd*3+255)/256,256,0,stream>>>(wT1, c1w, 3);
  k_wT<<<(Dd*Dd*6+255)/256,256,0,stream>>>(wT2, c2w, 6);
  k_wT<<<(Dd*Dd*9+255)/256,256,0,stream>>>(wT3, c3w, 9);

  // ---- ProteinCNN: embed(str 900)->conv1(S1)->conv2(S2)->conv3(S3 in cnnA) ----
  k_embed<<<dim3((LPc+127)/128, Dd, Bc),128,0,stream>>>(cnnB, vp, emb);
  k_convg<3><<<dim3(15,2,Bc),256,0,stream>>>(cnnA, cnnB, wT1, cbv, 900, 898, 900, S1, 0);
  k_bnc_stats<<<Dd,256,0,stream>>>(bnm,bnr,cnnA,898,S1);
  { size_t t0=(size_t)Bc*Dd*898;
    k_bnc_apply<<<(unsigned)((t0+255)/256),256,0,stream>>>(cnnA,bnm,bnr,bng,bnb,898,S1,0); }
  k_convg<6><<<dim3(14,2,Bc),256,0,stream>>>(cnnB, cnnA, wT2, cbv, 898, 893, S1, S2, 128);
  k_bnc_stats<<<Dd,256,0,stream>>>(bnm,bnr,cnnB,893,S2);
  { size_t t1=(size_t)Bc*Dd*893;
    k_bnc_apply<<<(unsigned)((t1+255)/256),256,0,stream>>>(cnnB,bnm,bnr,bng,bnb,893,S2,128); }
  k_convg<9><<<dim3(14,2,Bc),256,0,stream>>>(cnnA, cnnB, wT3, cbv, 893, 885, S2, S3, 256);
  k_bnc_stats<<<Dd,256,0,stream>>>(bnm,bnr,cnnA,885,S3);
  { size_t t2=(size_t)Bc*Dd*885;
    k_bnc_apply<<<(unsigned)((t2+255)/256),256,0,stream>>>(cnnA,bnm,bnr,bng,bnb,885,S3,256); }

  // ---- q branch: chunked Gq (upper tiles) / Sq ----
  hipMemsetAsync(Gq, 0, (size_t)Bc*HKc*HKc*sizeof(float), stream);
  hipMemsetAsync(Sq, 0, (size_t)Bc*HKc*sizeof(float), stream);
  for (int t0c = 0; t0c < LQ; t0c += CHT){
    int Tc = LQ - t0c; if (Tc > CHT) Tc = CHT;
    k_qgemm_tile<<<dim3(12,(Tc+63)/64,Bc),256,0,stream>>>(qc, cnnA, Wq, bq, t0c, Tc);
    k_colsum_acc<<<dim3(3,Bc),256,0,stream>>>(Sq, qc, Tc);
    k_gram_acc_sym<<<dim3(78,Bc),256,0,stream>>>(Gq, qc, Tc);
  }

  // ---- dense adjacency ----
  hipMemsetAsync(Adj, 0, ADJ*sizeof(float), stream);
  k_build_adj<<<(Ec+255)/256,256,0,stream>>>(Adj, esrc, edst);

  // ---- three GCN branches + Gram-fused BAN + MLPs ----
  for (int g=0; g<3; g++){
    k_h0<<<Nn,Dd,0,stream>>>(A1, node_h, W_init);
    { int wo=g*3+0;
      k_gcn_fused<<<dim3(37,Bc),128,0,stream>>>(A3, Adj, A1, gcn_W+(size_t)wo*Dd*Dd, gcn_b+(size_t)wo*Dd,
                                                gcn_Wr+(size_t)wo*Dd*Dd, gcn_br+(size_t)wo*Dd); }
    { int wo=g*3+1;
      k_gcn_fused<<<dim3(37,Bc),128,0,stream>>>(A2t, Adj, A3, gcn_W+(size_t)wo*Dd*Dd, gcn_b+(size_t)wo*Dd,
                                                gcn_Wr+(size_t)wo*Dd*Dd, gcn_br+(size_t)wo*Dd); }
    { int wo=g*3+2;
      k_gcn_fused<<<dim3(37,Bc),128,0,stream>>>(A0, Adj, A2t, gcn_W+(size_t)wo*Dd*Dd, gcn_b+(size_t)wo*Dd,
                                                gcn_Wr+(size_t)wo*Dd*Dd, gcn_br+(size_t)wo*Dd); }

    hipMemsetAsync(fbuf, 0, (size_t)Bc*HKc*sizeof(float), stream);
    for (int p=0; p<2; p++){
      int bbase = p*16;
      k_vgemm8<<<dim3(3,(16*NPGc)/8),256,0,stream>>>(vbuf, A0, Wv, bvv, bbase*NPGc);
      k_colsum_v<<<dim3(3,16),256,0,stream>>>(Sv, vbuf, bbase);
      k_gramf_sym<<<dim3(78,1,16),256,0,stream>>>(fbuf, vbuf, Gq, hmat, bbase);
    }
    k_pool<<<(Bc*256+255)/256,256,0,stream>>>(fpool, fbuf, Sv, Sq, hbias);
    k_bnfeat<<<256,32,0,stream>>>(fpool, fpool, bang, banb, 256);
    k_mlp<<<dim3(2,Bc),256,0,stream>>>(hh1, fpool, mw1, mb1, 256, 512, 1);
    k_bnfeat<<<512,32,0,stream>>>(hh1,hh1,g1,bb1,512);
    k_mlp<<<dim3(2,Bc),256,0,stream>>>(hh2, hh1, mw2, mb2, 512, 512, 1);
    k_bnfeat<<<512,32,0,stream>>>(hh2,hh2,g2,bb2,512);
    k_mlp<<<dim3(1,Bc),256,0,stream>>>(hh3, hh2, mw3, mb3, 512, 128, 1);
    k_bnfeat<<<128,32,0,stream>>>(hh3,hh3,g3,bb3,128);
    k_score<<<1,32,0,stream>>>(sc + 32*g, hh3, mw4, mb4);
  }

  k_out<<<1,32,0,stream>>>((float*)d_out, sc);
}